// Round 4
// baseline (25464.719 us; speedup 1.0000x reference)
//
#include <hip/hip_runtime.h>
#include <hip/hip_bf16.h>

// ---------------- workspace layout (float offsets) ----------------
// xd   [8,256,32,32]      q/k/v [32,1024,64]      att  [32,1024,64]
// spart[4096,1024]        score [32,1024]         idx  [32,256] (int)
// cout [8,256,64,64]      y     [8,256,64,64]     t1   [8,256,64,64]
constexpr size_t OFF_XD    = 0;
constexpr size_t OFF_Q     = 2097152;
constexpr size_t OFF_K     = 4194304;
constexpr size_t OFF_V     = 6291456;
constexpr size_t OFF_ATT   = 8388608;
constexpr size_t OFF_SPART = 10485760;
constexpr size_t OFF_SCORE = 14680064;
constexpr size_t OFF_IDX   = 14712832;
constexpr size_t OFF_COUT  = 14721024;
constexpr size_t OFF_Y     = 23109632;
constexpr size_t OFF_T1    = 31498240;
constexpr size_t WS_FLOATS = 39886848;

// ---------------- 1. down conv: 4x4 stride2 pad1, 256->256 ----------------
__global__ __launch_bounds__(256) void k_conv_down(const float* __restrict__ x,
    const float* __restrict__ w, const float* __restrict__ bias, float* __restrict__ xd) {
  int blk = blockIdx.x;              // b*1024 + co*4 + tile
  int tile = blk & 3;
  int co = (blk >> 2) & 255;
  int b = blk >> 10;
  __shared__ float wl[4096];
  for (int i = threadIdx.x; i < 4096; i += 256) wl[i] = w[co * 4096 + i];
  __syncthreads();
  int pix = tile * 256 + threadIdx.x;
  int oh = pix >> 5, ow = pix & 31;
  int ih0 = oh * 2 - 1, iw0 = ow * 2 - 1;
  float acc = bias[co];
  const float* xb = x + ((size_t)b * 256) * 4096;
  for (int ci = 0; ci < 256; ++ci) {
    const float* xc = xb + (size_t)ci * 4096;
    const float* wc = wl + ci * 16;
#pragma unroll
    for (int kh = 0; kh < 4; ++kh) {
      int ih = ih0 + kh;
      bool okh = ((unsigned)ih < 64u);
#pragma unroll
      for (int kw = 0; kw < 4; ++kw) {
        int iw = iw0 + kw;
        float xv = 0.f;
        if (okh && ((unsigned)iw < 64u)) xv = xc[ih * 64 + iw];
        acc = fmaf(xv, wc[kh * 4 + kw], acc);
      }
    }
  }
  xd[((size_t)b * 256 + co) * 1024 + pix] = acc;
}

// ---------------- 2. QKV gemm for coarse stage (with xd transpose gather) ----------------
__global__ __launch_bounds__(192) void k_qkv_coarse(const float* __restrict__ xd,
    const float* __restrict__ W, const float* __restrict__ bias,
    float* __restrict__ q, float* __restrict__ k, float* __restrict__ v) {
  int row = blockIdx.x;              // bn*1024 + i
  int bn = row >> 10, i = row & 1023;
  int b = bn >> 2, n = bn & 3;
  __shared__ float t[64];
  if (threadIdx.x < 64)
    t[threadIdx.x] = xd[((size_t)(b * 256 + n * 64 + threadIdx.x)) * 1024 + i];
  __syncthreads();
  int e = threadIdx.x;               // 0..191
  float acc = bias[e];
  const float* wr = W + e * 64;
#pragma unroll
  for (int d = 0; d < 64; ++d) acc = fmaf(t[d], wr[d], acc);
  float* dst = (e < 64) ? q : (e < 128) ? k : v;
  dst[(size_t)row * 64 + (e & 63)] = acc;
}

// ---------------- 3. QKV gemm for topk stage (token gather, clamped idx) --------
__global__ __launch_bounds__(192) void k_qkv_topk(const float* __restrict__ cout,
    const int* __restrict__ idx, const float* __restrict__ W, const float* __restrict__ bias,
    float* __restrict__ q, float* __restrict__ k, float* __restrict__ v) {
  int row = blockIdx.x;              // bn*1024 + t
  int bn = row >> 10, t = row & 1023;
  int b = bn >> 2, n = bn & 3;
  int kk = t >> 2, ab = t & 3;
  int a = ab >> 1, bi = ab & 1;
  __shared__ float tl[64];
  __shared__ int ps;
  if (threadIdx.x == 0) ps = idx[bn * 256 + kk] & 1023;   // clamp: never fault
  __syncthreads();
  int p = ps;
  int sh = (p >> 5) * 2 + a, sw = (p & 31) * 2 + bi;
  if (threadIdx.x < 64)
    tl[threadIdx.x] = cout[((size_t)(b * 256 + n * 64 + threadIdx.x)) * 4096 + sh * 64 + sw];
  __syncthreads();
  int e = threadIdx.x;
  float acc = bias[e];
  const float* wr = W + e * 64;
#pragma unroll
  for (int d = 0; d < 64; ++d) acc = fmaf(tl[d], wr[d], acc);
  float* dst = (e < 64) ? q : (e < 128) ? k : v;
  dst[(size_t)row * 64 + (e & 63)] = acc;
}

// ---------------- 4. attention: rows<-K, cols<-Q, softmax over cols ----------------
__device__ __forceinline__ float wave_max(float x) {
#pragma unroll
  for (int off = 32; off > 0; off >>= 1) x = fmaxf(x, __shfl_xor(x, off, 64));
  return x;
}
__device__ __forceinline__ float wave_sum(float x) {
#pragma unroll
  for (int off = 32; off > 0; off >>= 1) x += __shfl_xor(x, off, 64);
  return x;
}

template <bool SCORE>
__global__ __launch_bounds__(512) void k_attn(
    const float* __restrict__ Q, const float* __restrict__ K,
    const float* __restrict__ V, float* __restrict__ O,
    float* __restrict__ spart) {
  int bn = blockIdx.x >> 7;          // /128
  int rb = blockIdx.x & 127;
  int wave = threadIdx.x >> 6;       // 0..7
  int lane = threadIdx.x & 63;
  int row = rb * 8 + wave;
  const float* qb = Q + (size_t)bn * 65536;
  const float* kb = K + (size_t)bn * 65536;
  const float* vb = V + (size_t)bn * 65536;

  __shared__ float sacc[1024];
  if (SCORE) {
    for (int i = threadIdx.x; i < 1024; i += 512) sacc[i] = 0.f;
    __syncthreads();
  }

  // K row of this wave (wave-uniform values)
  float ks[64];
  {
    const float4* kp = (const float4*)(kb + (size_t)row * 64);
#pragma unroll
    for (int t = 0; t < 16; ++t) {
      float4 kv = kp[t];
      ks[t * 4 + 0] = kv.x;
      ks[t * 4 + 1] = kv.y;
      ks[t * 4 + 2] = kv.z;
      ks[t * 4 + 3] = kv.w;
    }
  }

  float m = -3.0e38f, l = 0.f;
  // pass A: row max + denom (online over 16 col-tiles of 64)
  for (int jt = 0; jt < 16; ++jt) {
    const float4* qp = (const float4*)(qb + (size_t)(jt * 64 + lane) * 64);
    float s = 0.f;
#pragma unroll
    for (int t = 0; t < 16; ++t) {
      float4 qv = qp[t];
      s = fmaf(qv.x, ks[t * 4 + 0], s);
      s = fmaf(qv.y, ks[t * 4 + 1], s);
      s = fmaf(qv.z, ks[t * 4 + 2], s);
      s = fmaf(qv.w, ks[t * 4 + 3], s);
    }
    float tm = wave_max(s);
    float mn = fmaxf(m, tm);
    float p = expf(s - mn);
    float ts = wave_sum(p);
    l = l * expf(m - mn) + ts;
    m = mn;
  }
  float inv = 1.f / l;

  // pass B: exact p, P·V, score accumulation
  float acc = 0.f;
  for (int jt = 0; jt < 16; ++jt) {
    const float4* qp = (const float4*)(qb + (size_t)(jt * 64 + lane) * 64);
    float s = 0.f;
#pragma unroll
    for (int t = 0; t < 16; ++t) {
      float4 qv = qp[t];
      s = fmaf(qv.x, ks[t * 4 + 0], s);
      s = fmaf(qv.y, ks[t * 4 + 1], s);
      s = fmaf(qv.z, ks[t * 4 + 2], s);
      s = fmaf(qv.w, ks[t * 4 + 3], s);
    }
    float p = expf(s - m) * inv;
    if (SCORE) atomicAdd(&sacc[jt * 64 + lane], p);
    const float* vp = vb + (size_t)jt * 4096 + lane;   // lane owns output dim d=lane
#pragma unroll
    for (int j = 0; j < 64; ++j) {
      float vv = vp[(size_t)j * 64];
      acc = fmaf(__shfl(p, j, 64), vv, acc);
    }
  }
  O[((size_t)bn * 1024 + row) * 64 + lane] = acc;
  if (SCORE) {
    __syncthreads();
    for (int i = threadIdx.x; i < 1024; i += 512)
      spart[((size_t)bn * 128 + rb) * 1024 + i] = sacc[i];
  }
}

// ---------------- 5. deterministic score reduction ----------------
__global__ __launch_bounds__(256) void k_score_reduce(const float* __restrict__ part,
                                                      float* __restrict__ score) {
  int j = blockIdx.x * 256 + threadIdx.x;   // 0..32767
  int bn = j >> 10, jj = j & 1023;
  float s = 0.f;
  for (int g = 0; g < 128; ++g) s += part[((size_t)bn * 128 + g) * 1024 + jj];
  score[j] = s;
}

// ---------------- 5b. default-init idx so it is never poison ----------------
__global__ __launch_bounds__(256) void k_idx_init(int* __restrict__ idx) {
  int j = blockIdx.x * 256 + threadIdx.x;   // 0..8191
  idx[j] = j & 255;
}

// ---------------- 6. top-K by rank (lax.top_k tie-break: lower index wins) --------
__global__ __launch_bounds__(1024) void k_topk(const float* __restrict__ score,
                                               int* __restrict__ idxout) {
  int bn = blockIdx.x;
  int t = threadIdx.x;
  __shared__ float s[1024];
  s[t] = score[bn * 1024 + t];
  __syncthreads();
  float my = s[t];
  int rank = 0;
  for (int j = 0; j < 1024; ++j) {
    float o = s[j];
    rank += (o > my) || (o == my && j < t);
  }
  if (rank < 256) idxout[bn * 256 + rank] = t;
}

// ---------------- 7. transposed conv: 4x4 stride2 pad1 ----------------
__global__ __launch_bounds__(256) void k_conv_up(const float* __restrict__ att,
    const float* __restrict__ w, const float* __restrict__ bias, float* __restrict__ cout) {
  int blk = blockIdx.x;              // (b*256 + co)*16 + tile
  int tile = blk & 15;
  int co = (blk >> 4) & 255;
  int b = blk >> 12;
  __shared__ float wl[4096];
  for (int i = threadIdx.x; i < 4096; i += 256) {
    int ci = i >> 4, kk = i & 15;
    wl[i] = w[(ci * 256 + co) * 16 + kk];
  }
  __syncthreads();
  int pix = tile * 256 + threadIdx.x;
  int oh = pix >> 6, ow = pix & 63;
  // valid taps: kh in {c0, c0+2}, ih = (oh+1-kh)/2
  int c0 = (oh + 1) & 1;
  int ihA = (oh + 1 - c0) >> 1;      // kh = c0
  int ihB = ihA - 1;                 // kh = c0+2
  bool vA = (ihA < 32), vB = (ihB >= 0);
  int d0 = (ow + 1) & 1;
  int iwX = (ow + 1 - d0) >> 1;      // kw = d0
  int iwY = iwX - 1;                 // kw = d0+2
  bool vX = (iwX < 32), vY = (iwY >= 0);
  float acc = bias[co];
  const float* ab0 = att + (size_t)(b * 4) * 65536;
  for (int ci = 0; ci < 256; ++ci) {
    int n = ci >> 6, d = ci & 63;
    const float* ap = ab0 + (size_t)n * 65536 + d;
    const float* wc = wl + ci * 16;
    if (vA) {
      if (vX) acc = fmaf(ap[(ihA * 32 + iwX) * 64], wc[c0 * 4 + d0], acc);
      if (vY) acc = fmaf(ap[(ihA * 32 + iwY) * 64], wc[c0 * 4 + d0 + 2], acc);
    }
    if (vB) {
      if (vX) acc = fmaf(ap[(ihB * 32 + iwX) * 64], wc[(c0 + 2) * 4 + d0], acc);
      if (vY) acc = fmaf(ap[(ihB * 32 + iwY) * 64], wc[(c0 + 2) * 4 + d0 + 2], acc);
    }
  }
  cout[((size_t)(b * 256 + co)) * 4096 + pix] = acc;
}

// ---------------- 8. y = coarse_out + region(patches part) ----------------
__global__ __launch_bounds__(256) void k_ybuild(const float* __restrict__ cout,
                                                float* __restrict__ y) {
  size_t e = (size_t)blockIdx.x * 256 + threadIdx.x;   // 8,388,608
  int flat = (int)(e & 4095);
  size_t bc = e >> 12;
  int p = flat >> 2, ab = flat & 3;
  int a = ab >> 1, bi = ab & 1;
  int src = ((p >> 5) * 2 + a) * 64 + (p & 31) * 2 + bi;
  const float* cb = cout + bc * 4096;
  y[e] = cb[flat] + cb[src];
}

// ---------------- 9. scatter-add attended tokens into y (clamped idx) ---------
__global__ __launch_bounds__(256) void k_scatter(const float* __restrict__ out2,
    const int* __restrict__ idx, float* __restrict__ y) {
  int e = blockIdx.x * 256 + threadIdx.x;   // 2,097,152
  int d = e & 63;
  int r = e >> 6;
  int ab = r & 3;
  int r2 = r >> 2;
  int kk = r2 & 255;
  int bn = r2 >> 8;
  int b = bn >> 2, n = bn & 3;
  int p = idx[bn * 256 + kk] & 1023;        // clamp: never fault
  int flat = p * 4 + ab;
  int t = kk * 4 + ab;
  y[((size_t)(b * 256 + n * 64 + d)) * 4096 + flat] +=
      out2[((size_t)bn * 1024 + t) * 64 + d];
}

// ---------------- 10. depthwise 3x3 + BN + relu6 ----------------
__global__ __launch_bounds__(256) void k_dw(const float* __restrict__ y,
    const float* __restrict__ w, const float* __restrict__ g, const float* __restrict__ bb,
    const float* __restrict__ mm, const float* __restrict__ vv, float* __restrict__ t1) {
  size_t e = (size_t)blockIdx.x * 256 + threadIdx.x;
  int pix = (int)(e & 4095);
  int c = (int)((e >> 12) & 255);
  int oh = pix >> 6, ow = pix & 63;
  const float* yb = y + (e - pix);
  float acc = 0.f;
#pragma unroll
  for (int kh = 0; kh < 3; ++kh) {
    int ih = oh - 1 + kh;
    if ((unsigned)ih >= 64u) continue;
#pragma unroll
    for (int kw = 0; kw < 3; ++kw) {
      int iw = ow - 1 + kw;
      if ((unsigned)iw >= 64u) continue;
      acc = fmaf(yb[ih * 64 + iw], w[c * 9 + kh * 3 + kw], acc);
    }
  }
  float s = g[c] * rsqrtf(vv[c] + 1e-5f);
  float val = acc * s + (bb[c] - mm[c] * s);
  t1[e] = fminf(fmaxf(val, 0.f), 6.f);
}

// ---------------- 11. pointwise 1x1 + BN + relu6 -> fp32 out ----------------
__global__ __launch_bounds__(256) void k_pw(const float* __restrict__ t1,
    const float* __restrict__ w, const float* __restrict__ g, const float* __restrict__ bb,
    const float* __restrict__ mm, const float* __restrict__ vv, float* __restrict__ out) {
  int blk = blockIdx.x;              // b*1024 + co*4 + tile
  int tile = blk & 3;
  int co = (blk >> 2) & 255;
  int b = blk >> 10;
  __shared__ float wl[256];
  wl[threadIdx.x] = w[co * 256 + threadIdx.x];
  __syncthreads();
  int pix0 = tile * 1024 + threadIdx.x * 4;
  const float4* tb = (const float4*)(t1 + (size_t)b * 256 * 4096 + pix0);
  float ax = 0.f, ay = 0.f, az = 0.f, aw = 0.f;
  for (int ci = 0; ci < 256; ++ci) {
    float4 tv = tb[(size_t)ci * 1024];
    float wv = wl[ci];
    ax = fmaf(tv.x, wv, ax);
    ay = fmaf(tv.y, wv, ay);
    az = fmaf(tv.z, wv, az);
    aw = fmaf(tv.w, wv, aw);
  }
  float s = g[co] * rsqrtf(vv[co] + 1e-5f);
  float bias = bb[co] - mm[co] * s;
  float4 o4;
  o4.x = fminf(fmaxf(ax * s + bias, 0.f), 6.f);
  o4.y = fminf(fmaxf(ay * s + bias, 0.f), 6.f);
  o4.z = fminf(fmaxf(az * s + bias, 0.f), 6.f);
  o4.w = fminf(fmaxf(aw * s + bias, 0.f), 6.f);
  *(float4*)(out + ((size_t)(b * 256 + co)) * 4096 + pix0) = o4;
}

// ---------------- launcher ----------------
extern "C" void kernel_launch(void* const* d_in, const int* in_sizes, int n_in,
                              void* d_out, int out_size, void* d_ws, size_t ws_size,
                              hipStream_t stream) {
  if (ws_size < WS_FLOATS * sizeof(float)) return;  // loud failure if scratch too small

  const float* x      = (const float*)d_in[0];
  const float* down_w = (const float*)d_in[1];
  const float* down_b = (const float*)d_in[2];
  const float* up_w   = (const float*)d_in[3];
  const float* up_b   = (const float*)d_in[4];
  const float* cqkv_w = (const float*)d_in[5];
  const float* cqkv_b = (const float*)d_in[6];
  const float* tqkv_w = (const float*)d_in[7];
  const float* tqkv_b = (const float*)d_in[8];
  const float* dww    = (const float*)d_in[9];
  const float* bn1g   = (const float*)d_in[10];
  const float* bn1b   = (const float*)d_in[11];
  const float* bn1m   = (const float*)d_in[12];
  const float* bn1v   = (const float*)d_in[13];
  const float* pww    = (const float*)d_in[14];
  const float* bn2g   = (const float*)d_in[15];
  const float* bn2b   = (const float*)d_in[16];
  const float* bn2m   = (const float*)d_in[17];
  const float* bn2v   = (const float*)d_in[18];

  float* ws    = (float*)d_ws;
  float* xd    = ws + OFF_XD;
  float* q     = ws + OFF_Q;
  float* k     = ws + OFF_K;
  float* v     = ws + OFF_V;
  float* att   = ws + OFF_ATT;     // coarse attn out; reused for out2
  float* spart = ws + OFF_SPART;
  float* score = ws + OFF_SCORE;
  int*   idx   = (int*)(ws + OFF_IDX);
  float* cout  = ws + OFF_COUT;
  float* y     = ws + OFF_Y;
  float* t1    = ws + OFF_T1;

  k_conv_down<<<8192, 256, 0, stream>>>(x, down_w, down_b, xd);
  k_qkv_coarse<<<32768, 192, 0, stream>>>(xd, cqkv_w, cqkv_b, q, k, v);
  k_attn<true><<<4096, 512, 0, stream>>>(q, k, v, att, spart);
  k_score_reduce<<<128, 256, 0, stream>>>(spart, score);
  k_idx_init<<<32, 256, 0, stream>>>(idx);
  k_topk<<<32, 1024, 0, stream>>>(score, idx);
  k_conv_up<<<32768, 256, 0, stream>>>(att, up_w, up_b, cout);
  k_qkv_topk<<<32768, 192, 0, stream>>>(cout, idx, tqkv_w, tqkv_b, q, k, v);
  k_attn<false><<<4096, 512, 0, stream>>>(q, k, v, att, spart);
  k_ybuild<<<32768, 256, 0, stream>>>(cout, y);
  k_scatter<<<8192, 256, 0, stream>>>(att, idx, y);
  k_dw<<<32768, 256, 0, stream>>>(y, dww, bn1g, bn1b, bn1m, bn1v, t1);
  k_pw<<<8192, 256, 0, stream>>>(t1, pww, bn2g, bn2b, bn2m, bn2v, (float*)d_out);
}

// Round 6
// 3800.891 us; speedup vs baseline: 6.6997x; 6.6997x over previous
//
#include <hip/hip_runtime.h>
#include <hip/hip_bf16.h>

// ---------------- workspace layout (float offsets) ----------------
// xd   [8,256,32,32]      q/k/v [32,1024,64]      att  [32,1024,64]
// spart[4096,1024]        score [32,1024]         idx  [32,256] (int)
// cout [8,256,64,64]      y     [8,256,64,64]     t1   [8,256,64,64]
// aliases: wt (1M fl) -> xd region (xd dead after k_qkv_coarse)
//          dwt (1M fl) -> spart region (spart dead until k_attn2<true>)
constexpr size_t OFF_XD    = 0;
constexpr size_t OFF_Q     = 2097152;
constexpr size_t OFF_K     = 4194304;
constexpr size_t OFF_V     = 6291456;
constexpr size_t OFF_ATT   = 8388608;
constexpr size_t OFF_SPART = 10485760;
constexpr size_t OFF_SCORE = 14680064;
constexpr size_t OFF_IDX   = 14712832;
constexpr size_t OFF_COUT  = 14721024;
constexpr size_t OFF_Y     = 23109632;
constexpr size_t OFF_T1    = 31498240;
constexpr size_t WS_FLOATS = 39886848;

// ---------------- 0a. transpose down_w [co][ci][kh][kw] -> dwt [ci][kk][co] ----
__global__ __launch_bounds__(256) void k_wt_dn(const float* __restrict__ w,
                                               float* __restrict__ dwt) {
  int idx = blockIdx.x * 256 + threadIdx.x;   // 1,048,576
  int co = idx & 255;
  int kk = (idx >> 8) & 15;
  int ci = idx >> 12;
  dwt[((size_t)(ci * 16 + kk)) * 256 + co] = w[((size_t)(co * 256 + ci)) * 16 + kk];
}

// ---------------- 0b. transpose up_w [ci][co][kh][kw] -> wt [cls][tap][ci][co] --
__global__ __launch_bounds__(256) void k_wt_up(const float* __restrict__ w,
                                               float* __restrict__ wt) {
  int idx = blockIdx.x * 256 + threadIdx.x;   // 1,048,576
  int co = idx & 255;
  int ci = (idx >> 8) & 255;
  int tp = idx >> 16;                         // 0..15
  int cls = tp >> 2, tap = tp & 3;
  int r = cls >> 1, s = cls & 1;
  int kh = (tap < 2) ? (r ? 0 : 1) : (r ? 2 : 3);
  int kw = ((tap & 1) == 0) ? (s ? 0 : 1) : (s ? 2 : 3);
  wt[idx] = w[((size_t)(ci * 256 + co)) * 16 + kh * 4 + kw];
}

// ---------------- 1. down conv v2: LDS-tiled, 4co x 4px per thread -------------
__global__ __launch_bounds__(256) void k_conv_down2(const float* __restrict__ x,
    const float* __restrict__ dwt, const float* __restrict__ bias,
    float* __restrict__ xd) {
  int blk = blockIdx.x;            // ((b*4 + cg)*16 + ihp)
  int ihp = blk & 15;
  int cg = (blk >> 4) & 3;
  int b = blk >> 6;
  int oh0 = ihp * 2;
  int co0 = cg * 64;
  int t = threadIdx.x;
  int cg4 = t >> 4;                // 16 co-groups of 4
  int px = t & 15;
  int i_loc = px >> 3;             // 0..1 (oh row)
  int j0 = (px & 7) << 2;          // 0..28 (ow)

  __shared__ float xs[4][6][68];
  __shared__ float ws[4][16][64];

  float acc[4][4];
#pragma unroll
  for (int ck = 0; ck < 4; ++ck) {
    float bv = bias[co0 + cg4 * 4 + ck];
#pragma unroll
    for (int jj = 0; jj < 4; ++jj) acc[ck][jj] = bv;
  }
  const float* xb = x + (size_t)b * 256 * 4096;

  for (int ci0 = 0; ci0 < 256; ci0 += 4) {
    __syncthreads();
    for (int idx = t; idx < 4 * 6 * 67; idx += 256) {
      int cl = idx / 402;
      int rem = idx - cl * 402;
      int row = rem / 67;
      int col = rem - row * 67;
      int ih = oh0 * 2 - 1 + row;
      int iw = col - 1;
      float v = 0.f;
      if ((unsigned)ih < 64u && (unsigned)iw < 64u)
        v = xb[(size_t)(ci0 + cl) * 4096 + ih * 64 + iw];
      xs[cl][row][col] = v;
    }
    for (int idx = t; idx < 4 * 16 * 64; idx += 256) {
      int cl = idx >> 10;
      int kk = (idx >> 6) & 15;
      int c = idx & 63;
      ws[cl][kk][c] = dwt[((size_t)(ci0 + cl) * 16 + kk) * 256 + co0 + c];
    }
    __syncthreads();
#pragma unroll
    for (int cl = 0; cl < 4; ++cl) {
      float xr[4][10];
#pragma unroll
      for (int rr = 0; rr < 4; ++rr)
#pragma unroll
        for (int u = 0; u < 10; ++u)
          xr[rr][u] = xs[cl][2 * i_loc + rr][2 * j0 + u];
#pragma unroll
      for (int ck = 0; ck < 4; ++ck) {
        int col = cg4 * 4 + ck;
#pragma unroll
        for (int kh = 0; kh < 4; ++kh)
#pragma unroll
          for (int kw = 0; kw < 4; ++kw) {
            float wv = ws[cl][kh * 4 + kw][col];
#pragma unroll
            for (int jj = 0; jj < 4; ++jj)
              acc[ck][jj] = fmaf(xr[kh][2 * jj + kw], wv, acc[ck][jj]);
          }
      }
    }
  }
#pragma unroll
  for (int ck = 0; ck < 4; ++ck)
#pragma unroll
    for (int jj = 0; jj < 4; ++jj)
      xd[((size_t)b * 256 + co0 + cg4 * 4 + ck) * 1024 + (oh0 + i_loc) * 32 + j0 + jj] =
          acc[ck][jj];
}

// ---------------- 2. QKV gemm for coarse stage ----------------
__global__ __launch_bounds__(192) void k_qkv_coarse(const float* __restrict__ xd,
    const float* __restrict__ W, const float* __restrict__ bias,
    float* __restrict__ q, float* __restrict__ k, float* __restrict__ v) {
  int row = blockIdx.x;              // bn*1024 + i
  int bn = row >> 10, i = row & 1023;
  int b = bn >> 2, n = bn & 3;
  __shared__ float t[64];
  if (threadIdx.x < 64)
    t[threadIdx.x] = xd[((size_t)(b * 256 + n * 64 + threadIdx.x)) * 1024 + i];
  __syncthreads();
  int e = threadIdx.x;               // 0..191
  float acc = bias[e];
  const float* wr = W + e * 64;
#pragma unroll
  for (int d = 0; d < 64; ++d) acc = fmaf(t[d], wr[d], acc);
  float* dst = (e < 64) ? q : (e < 128) ? k : v;
  dst[(size_t)row * 64 + (e & 63)] = acc;
}

// ---------------- 3. QKV gemm for topk stage ----------------
__global__ __launch_bounds__(192) void k_qkv_topk(const float* __restrict__ cout,
    const int* __restrict__ idx, const float* __restrict__ W, const float* __restrict__ bias,
    float* __restrict__ q, float* __restrict__ k, float* __restrict__ v) {
  int row = blockIdx.x;              // bn*1024 + t
  int bn = row >> 10, t = row & 1023;
  int b = bn >> 2, n = bn & 3;
  int kk = t >> 2, ab = t & 3;
  int a = ab >> 1, bi = ab & 1;
  __shared__ float tl[64];
  __shared__ int ps;
  if (threadIdx.x == 0) ps = idx[bn * 256 + kk] & 1023;
  __syncthreads();
  int p = ps;
  int sh = (p >> 5) * 2 + a, sw = (p & 31) * 2 + bi;
  if (threadIdx.x < 64)
    tl[threadIdx.x] = cout[((size_t)(b * 256 + n * 64 + threadIdx.x)) * 4096 + sh * 64 + sw];
  __syncthreads();
  int e = threadIdx.x;
  float acc = bias[e];
  const float* wr = W + e * 64;
#pragma unroll
  for (int d = 0; d < 64; ++d) acc = fmaf(tl[d], wr[d], acc);
  float* dst = (e < 64) ? q : (e < 128) ? k : v;
  dst[(size_t)row * 64 + (e & 63)] = acc;
}

// ---------------- 4. attention v2: LDS-staged, 2 K-rows per wave ---------------
__device__ __forceinline__ float wave_max(float x) {
#pragma unroll
  for (int off = 32; off > 0; off >>= 1) x = fmaxf(x, __shfl_xor(x, off, 64));
  return x;
}
__device__ __forceinline__ float wave_sum(float x) {
#pragma unroll
  for (int off = 32; off > 0; off >>= 1) x += __shfl_xor(x, off, 64);
  return x;
}

template <bool SCORE>
__global__ __launch_bounds__(256) void k_attn2(
    const float* __restrict__ Q, const float* __restrict__ K,
    const float* __restrict__ V, float* __restrict__ O,
    float* __restrict__ spart) {
  int bn = blockIdx.x >> 7;          // /128
  int rb = blockIdx.x & 127;
  int wave = threadIdx.x >> 6;       // 0..3
  int lane = threadIdx.x & 63;
  int tid = threadIdx.x;
  int row0 = rb * 8 + wave * 2;      // this wave: rows row0, row0+1
  const float* qb = Q + (size_t)bn * 65536;
  const float* kb = K + (size_t)bn * 65536;
  const float* vb = V + (size_t)bn * 65536;

  __shared__ float qs[64 * 68];
  __shared__ float vsT[64 * 68];
  __shared__ float sacc[1024];
  if (SCORE)
    for (int i = tid; i < 1024; i += 256) sacc[i] = 0.f;

  // K rows -> regs (wave-uniform addresses)
  float k0[64], k1[64];
  {
    const float4* kp0 = (const float4*)(kb + (size_t)row0 * 64);
    const float4* kp1 = (const float4*)(kb + (size_t)(row0 + 1) * 64);
#pragma unroll
    for (int t = 0; t < 16; ++t) {
      float4 a = kp0[t];
      k0[4 * t] = a.x; k0[4 * t + 1] = a.y; k0[4 * t + 2] = a.z; k0[4 * t + 3] = a.w;
      float4 c = kp1[t];
      k1[4 * t] = c.x; k1[4 * t + 1] = c.y; k1[4 * t + 2] = c.z; k1[4 * t + 3] = c.w;
    }
  }

  float m0 = -3.0e38f, m1 = -3.0e38f, l0 = 0.f, l1 = 0.f;

  // ---- pass A: online max/denom ----
  for (int jt = 0; jt < 16; ++jt) {
    __syncthreads();
#pragma unroll
    for (int u = 0; u < 4; ++u) {
      int g = tid + 256 * u;
      int rr = g >> 4, c4 = g & 15;
      float4 qv = *(const float4*)(qb + (size_t)(jt * 64 + rr) * 64 + c4 * 4);
      *(float4*)&qs[rr * 68 + c4 * 4] = qv;
    }
    __syncthreads();
    float s0 = 0.f, s1 = 0.f;
#pragma unroll
    for (int t = 0; t < 16; ++t) {
      float4 qv = *(const float4*)&qs[lane * 68 + t * 4];
      s0 = fmaf(qv.x, k0[4 * t], s0); s0 = fmaf(qv.y, k0[4 * t + 1], s0);
      s0 = fmaf(qv.z, k0[4 * t + 2], s0); s0 = fmaf(qv.w, k0[4 * t + 3], s0);
      s1 = fmaf(qv.x, k1[4 * t], s1); s1 = fmaf(qv.y, k1[4 * t + 1], s1);
      s1 = fmaf(qv.z, k1[4 * t + 2], s1); s1 = fmaf(qv.w, k1[4 * t + 3], s1);
    }
    float tm0 = wave_max(s0);
    float mn0 = fmaxf(m0, tm0);
    float p0 = expf(s0 - mn0);
    float ts0 = wave_sum(p0);
    l0 = l0 * expf(m0 - mn0) + ts0;
    m0 = mn0;
    float tm1 = wave_max(s1);
    float mn1 = fmaxf(m1, tm1);
    float p1 = expf(s1 - mn1);
    float ts1 = wave_sum(p1);
    l1 = l1 * expf(m1 - mn1) + ts1;
    m1 = mn1;
  }
  float inv0 = 1.f / l0, inv1 = 1.f / l1;

  // ---- pass B: exact p, P.V, score ----
  float acc0 = 0.f, acc1 = 0.f;
  for (int jt = 0; jt < 16; ++jt) {
    __syncthreads();
#pragma unroll
    for (int u = 0; u < 4; ++u) {
      int g = tid + 256 * u;
      int rr = g >> 4, c4 = g & 15;
      float4 qv = *(const float4*)(qb + (size_t)(jt * 64 + rr) * 64 + c4 * 4);
      *(float4*)&qs[rr * 68 + c4 * 4] = qv;
    }
    {  // V tile: per-thread 4x4 block transpose
      int d4 = tid & 15;
      int jb = (tid >> 4) * 4;
      float4 v0 = *(const float4*)(vb + (size_t)(jt * 64 + jb + 0) * 64 + d4 * 4);
      float4 v1 = *(const float4*)(vb + (size_t)(jt * 64 + jb + 1) * 64 + d4 * 4);
      float4 v2 = *(const float4*)(vb + (size_t)(jt * 64 + jb + 2) * 64 + d4 * 4);
      float4 v3 = *(const float4*)(vb + (size_t)(jt * 64 + jb + 3) * 64 + d4 * 4);
      *(float4*)&vsT[(d4 * 4 + 0) * 68 + jb] = make_float4(v0.x, v1.x, v2.x, v3.x);
      *(float4*)&vsT[(d4 * 4 + 1) * 68 + jb] = make_float4(v0.y, v1.y, v2.y, v3.y);
      *(float4*)&vsT[(d4 * 4 + 2) * 68 + jb] = make_float4(v0.z, v1.z, v2.z, v3.z);
      *(float4*)&vsT[(d4 * 4 + 3) * 68 + jb] = make_float4(v0.w, v1.w, v2.w, v3.w);
    }
    __syncthreads();
    float s0 = 0.f, s1 = 0.f;
#pragma unroll
    for (int t = 0; t < 16; ++t) {
      float4 qv = *(const float4*)&qs[lane * 68 + t * 4];
      s0 = fmaf(qv.x, k0[4 * t], s0); s0 = fmaf(qv.y, k0[4 * t + 1], s0);
      s0 = fmaf(qv.z, k0[4 * t + 2], s0); s0 = fmaf(qv.w, k0[4 * t + 3], s0);
      s1 = fmaf(qv.x, k1[4 * t], s1); s1 = fmaf(qv.y, k1[4 * t + 1], s1);
      s1 = fmaf(qv.z, k1[4 * t + 2], s1); s1 = fmaf(qv.w, k1[4 * t + 3], s1);
    }
    float p0 = expf(s0 - m0) * inv0;
    float p1 = expf(s1 - m1) * inv1;
    if (SCORE) atomicAdd(&sacc[jt * 64 + lane], p0 + p1);
    // PV: lane owns output dim d = lane; j ascending
#pragma unroll
    for (int j4 = 0; j4 < 16; ++j4) {
      float4 vv = *(const float4*)&vsT[lane * 68 + j4 * 4];
      acc0 = fmaf(__shfl(p0, j4 * 4 + 0, 64), vv.x, acc0);
      acc0 = fmaf(__shfl(p0, j4 * 4 + 1, 64), vv.y, acc0);
      acc0 = fmaf(__shfl(p0, j4 * 4 + 2, 64), vv.z, acc0);
      acc0 = fmaf(__shfl(p0, j4 * 4 + 3, 64), vv.w, acc0);
      acc1 = fmaf(__shfl(p1, j4 * 4 + 0, 64), vv.x, acc1);
      acc1 = fmaf(__shfl(p1, j4 * 4 + 1, 64), vv.y, acc1);
      acc1 = fmaf(__shfl(p1, j4 * 4 + 2, 64), vv.z, acc1);
      acc1 = fmaf(__shfl(p1, j4 * 4 + 3, 64), vv.w, acc1);
    }
  }
  O[((size_t)bn * 1024 + row0) * 64 + lane] = acc0;
  O[((size_t)bn * 1024 + row0 + 1) * 64 + lane] = acc1;
  if (SCORE) {
    __syncthreads();
    for (int i = tid; i < 1024; i += 256)
      spart[((size_t)bn * 128 + rb) * 1024 + i] = sacc[i];
  }
}

// ---------------- 5. deterministic score reduction ----------------
__global__ __launch_bounds__(256) void k_score_reduce(const float* __restrict__ part,
                                                      float* __restrict__ score) {
  int j = blockIdx.x * 256 + threadIdx.x;   // 0..32767
  int bn = j >> 10, jj = j & 1023;
  float s = 0.f;
  for (int g = 0; g < 128; ++g) s += part[((size_t)bn * 128 + g) * 1024 + jj];
  score[j] = s;
}

// ---------------- 5b. default-init idx ----------------
__global__ __launch_bounds__(256) void k_idx_init(int* __restrict__ idx) {
  int j = blockIdx.x * 256 + threadIdx.x;
  idx[j] = j & 255;
}

// ---------------- 6. top-K by rank ----------------
__global__ __launch_bounds__(1024) void k_topk(const float* __restrict__ score,
                                               int* __restrict__ idxout) {
  int bn = blockIdx.x;
  int t = threadIdx.x;
  __shared__ float s[1024];
  s[t] = score[bn * 1024 + t];
  __syncthreads();
  float my = s[t];
  int rank = 0;
  for (int j = 0; j < 1024; ++j) {
    float o = s[j];
    rank += (o > my) || (o == my && j < t);
  }
  if (rank < 256) idxout[bn * 256 + rank] = t;
}

// ---------------- 7. transposed conv v2: class-split, LDS-tiled ----------------
__global__ __launch_bounds__(256) void k_conv_up2(const float* __restrict__ att,
    const float* __restrict__ wt, const float* __restrict__ bias,
    float* __restrict__ cout) {
  int blk = blockIdx.x;              // ((b*4+cls)*4 + cg)*16 + ip
  int ip = blk & 15;
  int cg = (blk >> 4) & 3;
  int cls = (blk >> 6) & 3;
  int b = blk >> 8;
  int r = cls >> 1, s = cls & 1;
  int i0 = ip * 2;
  int co0 = cg * 64;
  int t = threadIdx.x;
  int cg4 = t >> 4;
  int px = t & 15;
  int i_loc = px >> 3;
  int j0 = (px & 7) << 2;

  __shared__ float xs[16][3][36];
  __shared__ float ws[16][4][64];

  float acc[4][4];
#pragma unroll
  for (int ck = 0; ck < 4; ++ck) {
    float bv = bias[co0 + cg4 * 4 + ck];
#pragma unroll
    for (int jj = 0; jj < 4; ++jj) acc[ck][jj] = bv;
  }
  int rbase = i0 + r;
  const float* ab = att + (size_t)b * 4 * 65536;
  int cs = j0 + s;

  for (int ci0 = 0; ci0 < 256; ci0 += 16) {
    __syncthreads();
    for (int idx = t; idx < 16 * 102; idx += 256) {
      int cl = idx / 102;
      int rem = idx - cl * 102;
      int rho = rem / 34;
      int c = rem - rho * 34;
      int ih = rbase + rho - 1;
      int iw = c - 1;
      int ci = ci0 + cl;
      int n = ci >> 6, d = ci & 63;
      float v = 0.f;
      if ((unsigned)ih < 32u && (unsigned)iw < 32u)
        v = ab[((size_t)n * 1024 + ih * 32 + iw) * 64 + d];
      xs[cl][rho][c] = v;
    }
    for (int idx = t; idx < 16 * 4 * 64; idx += 256) {
      int cl = idx >> 8;
      int tap = (idx >> 6) & 3;
      int c = idx & 63;
      ws[cl][tap][c] = wt[(((size_t)(cls * 4 + tap) * 256) + ci0 + cl) * 256 + co0 + c];
    }
    __syncthreads();
#pragma unroll
    for (int cl = 0; cl < 16; ++cl) {
      float xA[5], xB[5];
#pragma unroll
      for (int u = 0; u < 5; ++u) {
        xA[u] = xs[cl][i_loc + 1][cs + u];
        xB[u] = xs[cl][i_loc][cs + u];
      }
#pragma unroll
      for (int ck = 0; ck < 4; ++ck) {
        int col = cg4 * 4 + ck;
        float wAA = ws[cl][0][col];
        float wAB = ws[cl][1][col];
        float wBA = ws[cl][2][col];
        float wBB = ws[cl][3][col];
#pragma unroll
        for (int jj = 0; jj < 4; ++jj) {
          float a = acc[ck][jj];
          a = fmaf(xA[jj + 1], wAA, a);
          a = fmaf(xA[jj],     wAB, a);
          a = fmaf(xB[jj + 1], wBA, a);
          a = fmaf(xB[jj],     wBB, a);
          acc[ck][jj] = a;
        }
      }
    }
  }
#pragma unroll
  for (int ck = 0; ck < 4; ++ck) {
    int oh = 2 * (i0 + i_loc) + r;
#pragma unroll
    for (int jj = 0; jj < 4; ++jj) {
      int ow = 2 * (j0 + jj) + s;
      cout[((size_t)b * 256 + co0 + cg4 * 4 + ck) * 4096 + oh * 64 + ow] = acc[ck][jj];
    }
  }
}

// ---------------- 8. y = coarse_out + region ----------------
__global__ __launch_bounds__(256) void k_ybuild(const float* __restrict__ cout,
                                                float* __restrict__ y) {
  size_t e = (size_t)blockIdx.x * 256 + threadIdx.x;
  int flat = (int)(e & 4095);
  size_t bc = e >> 12;
  int p = flat >> 2, ab = flat & 3;
  int a = ab >> 1, bi = ab & 1;
  int src = ((p >> 5) * 2 + a) * 64 + (p & 31) * 2 + bi;
  const float* cb = cout + bc * 4096;
  y[e] = cb[flat] + cb[src];
}

// ---------------- 9. scatter-add attended tokens ----------------
__global__ __launch_bounds__(256) void k_scatter(const float* __restrict__ out2,
    const int* __restrict__ idx, float* __restrict__ y) {
  int e = blockIdx.x * 256 + threadIdx.x;
  int d = e & 63;
  int r = e >> 6;
  int ab = r & 3;
  int r2 = r >> 2;
  int kk = r2 & 255;
  int bn = r2 >> 8;
  int b = bn >> 2, n = bn & 3;
  int p = idx[bn * 256 + kk] & 1023;
  int flat = p * 4 + ab;
  int t = kk * 4 + ab;
  y[((size_t)(b * 256 + n * 64 + d)) * 4096 + flat] +=
      out2[((size_t)bn * 1024 + t) * 64 + d];
}

// ---------------- 10. depthwise 3x3 + BN + relu6 ----------------
__global__ __launch_bounds__(256) void k_dw(const float* __restrict__ y,
    const float* __restrict__ w, const float* __restrict__ g, const float* __restrict__ bb,
    const float* __restrict__ mm, const float* __restrict__ vv, float* __restrict__ t1) {
  size_t e = (size_t)blockIdx.x * 256 + threadIdx.x;
  int pix = (int)(e & 4095);
  int c = (int)((e >> 12) & 255);
  int oh = pix >> 6, ow = pix & 63;
  const float* yb = y + (e - pix);
  float acc = 0.f;
#pragma unroll
  for (int kh = 0; kh < 3; ++kh) {
    int ih = oh - 1 + kh;
    if ((unsigned)ih >= 64u) continue;
#pragma unroll
    for (int kw = 0; kw < 3; ++kw) {
      int iw = ow - 1 + kw;
      if ((unsigned)iw >= 64u) continue;
      acc = fmaf(yb[ih * 64 + iw], w[c * 9 + kh * 3 + kw], acc);
    }
  }
  float s = g[c] * rsqrtf(vv[c] + 1e-5f);
  float val = acc * s + (bb[c] - mm[c] * s);
  t1[e] = fminf(fmaxf(val, 0.f), 6.f);
}

// ---------------- 11. pointwise 1x1 + BN + relu6 -> fp32 out ----------------
__global__ __launch_bounds__(256) void k_pw(const float* __restrict__ t1,
    const float* __restrict__ w, const float* __restrict__ g, const float* __restrict__ bb,
    const float* __restrict__ mm, const float* __restrict__ vv, float* __restrict__ out) {
  int blk = blockIdx.x;
  int tile = blk & 3;
  int co = (blk >> 2) & 255;
  int b = blk >> 10;
  __shared__ float wl[256];
  wl[threadIdx.x] = w[co * 256 + threadIdx.x];
  __syncthreads();
  int pix0 = tile * 1024 + threadIdx.x * 4;
  const float4* tb = (const float4*)(t1 + (size_t)b * 256 * 4096 + pix0);
  float ax = 0.f, ay = 0.f, az = 0.f, aw = 0.f;
  for (int ci = 0; ci < 256; ++ci) {
    float4 tv = tb[(size_t)ci * 1024];
    float wv = wl[ci];
    ax = fmaf(tv.x, wv, ax);
    ay = fmaf(tv.y, wv, ay);
    az = fmaf(tv.z, wv, az);
    aw = fmaf(tv.w, wv, aw);
  }
  float s = g[co] * rsqrtf(vv[co] + 1e-5f);
  float bias = bb[co] - mm[co] * s;
  float4 o4;
  o4.x = fminf(fmaxf(ax * s + bias, 0.f), 6.f);
  o4.y = fminf(fmaxf(ay * s + bias, 0.f), 6.f);
  o4.z = fminf(fmaxf(az * s + bias, 0.f), 6.f);
  o4.w = fminf(fmaxf(aw * s + bias, 0.f), 6.f);
  *(float4*)(out + ((size_t)(b * 256 + co)) * 4096 + pix0) = o4;
}

// ---------------- launcher ----------------
extern "C" void kernel_launch(void* const* d_in, const int* in_sizes, int n_in,
                              void* d_out, int out_size, void* d_ws, size_t ws_size,
                              hipStream_t stream) {
  if (ws_size < WS_FLOATS * sizeof(float)) return;

  const float* x      = (const float*)d_in[0];
  const float* down_w = (const float*)d_in[1];
  const float* down_b = (const float*)d_in[2];
  const float* up_w   = (const float*)d_in[3];
  const float* up_b   = (const float*)d_in[4];
  const float* cqkv_w = (const float*)d_in[5];
  const float* cqkv_b = (const float*)d_in[6];
  const float* tqkv_w = (const float*)d_in[7];
  const float* tqkv_b = (const float*)d_in[8];
  const float* dww    = (const float*)d_in[9];
  const float* bn1g   = (const float*)d_in[10];
  const float* bn1b   = (const float*)d_in[11];
  const float* bn1m   = (const float*)d_in[12];
  const float* bn1v   = (const float*)d_in[13];
  const float* pww    = (const float*)d_in[14];
  const float* bn2g   = (const float*)d_in[15];
  const float* bn2b   = (const float*)d_in[16];
  const float* bn2m   = (const float*)d_in[17];
  const float* bn2v   = (const float*)d_in[18];

  float* ws    = (float*)d_ws;
  float* xd    = ws + OFF_XD;
  float* q     = ws + OFF_Q;
  float* k     = ws + OFF_K;
  float* v     = ws + OFF_V;
  float* att   = ws + OFF_ATT;
  float* spart = ws + OFF_SPART;
  float* score = ws + OFF_SCORE;
  int*   idx   = (int*)(ws + OFF_IDX);
  float* cout  = ws + OFF_COUT;
  float* y     = ws + OFF_Y;
  float* t1    = ws + OFF_T1;
  float* dwt   = ws + OFF_SPART;   // alias: spart dead until k_attn2<true>
  float* wt    = ws + OFF_XD;      // alias: xd dead after k_qkv_coarse

  k_wt_dn<<<4096, 256, 0, stream>>>(down_w, dwt);
  k_conv_down2<<<512, 256, 0, stream>>>(x, dwt, down_b, xd);
  k_qkv_coarse<<<32768, 192, 0, stream>>>(xd, cqkv_w, cqkv_b, q, k, v);
  k_wt_up<<<4096, 256, 0, stream>>>(up_w, wt);          // overwrites xd region
  k_attn2<true><<<4096, 256, 0, stream>>>(q, k, v, att, spart);  // overwrites dwt
  k_score_reduce<<<128, 256, 0, stream>>>(spart, score);
  k_idx_init<<<32, 256, 0, stream>>>(idx);
  k_topk<<<32, 1024, 0, stream>>>(score, idx);
  k_conv_up2<<<2048, 256, 0, stream>>>(att, wt, up_b, cout);
  k_qkv_topk<<<32768, 192, 0, stream>>>(cout, idx, tqkv_w, tqkv_b, q, k, v);
  k_attn2<false><<<4096, 256, 0, stream>>>(q, k, v, att, spart);
  k_ybuild<<<32768, 256, 0, stream>>>(cout, y);
  k_scatter<<<8192, 256, 0, stream>>>(att, idx, y);
  k_dw<<<32768, 256, 0, stream>>>(y, dww, bn1g, bn1b, bn1m, bn1v, t1);
  k_pw<<<8192, 256, 0, stream>>>(t1, pww, bn2g, bn2b, bn2m, bn2v, (float*)d_out);
}

// Round 7
// 2129.393 us; speedup vs baseline: 11.9587x; 1.7850x over previous
//
#include <hip/hip_runtime.h>
#include <hip/hip_bf16.h>

// ---------------- workspace layout (float offsets) ----------------
// xd   [8,256,32,32]      q/k/v [32,1024,64]      att  [32,1024,64]
// spart[32,16,1024]       score [32,1024]         idx  [32,256] (int)
// cout [8,256,64,64]      y     [8,256,64,64]     t1   [8,256,64,64]
// aliases: wt (1M fl) -> xd region (xd dead after k_qkv_coarse)
//          dwt (1M fl) -> spart region (spart dead until k_attn3<true>)
constexpr size_t OFF_XD    = 0;
constexpr size_t OFF_Q     = 2097152;
constexpr size_t OFF_K     = 4194304;
constexpr size_t OFF_V     = 6291456;
constexpr size_t OFF_ATT   = 8388608;
constexpr size_t OFF_SPART = 10485760;
constexpr size_t OFF_SCORE = 14680064;
constexpr size_t OFF_IDX   = 14712832;
constexpr size_t OFF_COUT  = 14721024;
constexpr size_t OFF_Y     = 23109632;
constexpr size_t OFF_T1    = 31498240;
constexpr size_t WS_FLOATS = 39886848;

// ---------------- 0a. transpose down_w [co][ci][kh][kw] -> dwt [ci][kk][co] ----
__global__ __launch_bounds__(256) void k_wt_dn(const float* __restrict__ w,
                                               float* __restrict__ dwt) {
  int idx = blockIdx.x * 256 + threadIdx.x;   // 1,048,576
  int co = idx & 255;
  int kk = (idx >> 8) & 15;
  int ci = idx >> 12;
  dwt[((size_t)(ci * 16 + kk)) * 256 + co] = w[((size_t)(co * 256 + ci)) * 16 + kk];
}

// ---------------- 0b. transpose up_w [ci][co][kh][kw] -> wt [cls][tap][ci][co] --
__global__ __launch_bounds__(256) void k_wt_up(const float* __restrict__ w,
                                               float* __restrict__ wt) {
  int idx = blockIdx.x * 256 + threadIdx.x;   // 1,048,576
  int co = idx & 255;
  int ci = (idx >> 8) & 255;
  int tp = idx >> 16;                         // 0..15
  int cls = tp >> 2, tap = tp & 3;
  int r = cls >> 1, s = cls & 1;
  int kh = (tap < 2) ? (r ? 0 : 1) : (r ? 2 : 3);
  int kw = ((tap & 1) == 0) ? (s ? 0 : 1) : (s ? 2 : 3);
  wt[idx] = w[((size_t)(ci * 256 + co)) * 16 + kh * 4 + kw];
}

// ---------------- 1. down conv v2: LDS-tiled, 4co x 4px per thread -------------
__global__ __launch_bounds__(256) void k_conv_down2(const float* __restrict__ x,
    const float* __restrict__ dwt, const float* __restrict__ bias,
    float* __restrict__ xd) {
  int blk = blockIdx.x;            // ((b*4 + cg)*16 + ihp)
  int ihp = blk & 15;
  int cg = (blk >> 4) & 3;
  int b = blk >> 6;
  int oh0 = ihp * 2;
  int co0 = cg * 64;
  int t = threadIdx.x;
  int cg4 = t >> 4;                // 16 co-groups of 4
  int px = t & 15;
  int i_loc = px >> 3;             // 0..1 (oh row)
  int j0 = (px & 7) << 2;          // 0..28 (ow)

  __shared__ float xs[4][6][68];
  __shared__ float ws[4][16][64];

  float acc[4][4];
#pragma unroll
  for (int ck = 0; ck < 4; ++ck) {
    float bv = bias[co0 + cg4 * 4 + ck];
#pragma unroll
    for (int jj = 0; jj < 4; ++jj) acc[ck][jj] = bv;
  }
  const float* xb = x + (size_t)b * 256 * 4096;

  for (int ci0 = 0; ci0 < 256; ci0 += 4) {
    __syncthreads();
    for (int idx = t; idx < 4 * 6 * 67; idx += 256) {
      int cl = idx / 402;
      int rem = idx - cl * 402;
      int row = rem / 67;
      int col = rem - row * 67;
      int ih = oh0 * 2 - 1 + row;
      int iw = col - 1;
      float v = 0.f;
      if ((unsigned)ih < 64u && (unsigned)iw < 64u)
        v = xb[(size_t)(ci0 + cl) * 4096 + ih * 64 + iw];
      xs[cl][row][col] = v;
    }
    for (int idx = t; idx < 4 * 16 * 64; idx += 256) {
      int cl = idx >> 10;
      int kk = (idx >> 6) & 15;
      int c = idx & 63;
      ws[cl][kk][c] = dwt[((size_t)(ci0 + cl) * 16 + kk) * 256 + co0 + c];
    }
    __syncthreads();
#pragma unroll
    for (int cl = 0; cl < 4; ++cl) {
      float xr[4][10];
#pragma unroll
      for (int rr = 0; rr < 4; ++rr)
#pragma unroll
        for (int u = 0; u < 10; ++u)
          xr[rr][u] = xs[cl][2 * i_loc + rr][2 * j0 + u];
#pragma unroll
      for (int ck = 0; ck < 4; ++ck) {
        int col = cg4 * 4 + ck;
#pragma unroll
        for (int kh = 0; kh < 4; ++kh)
#pragma unroll
          for (int kw = 0; kw < 4; ++kw) {
            float wv = ws[cl][kh * 4 + kw][col];
#pragma unroll
            for (int jj = 0; jj < 4; ++jj)
              acc[ck][jj] = fmaf(xr[kh][2 * jj + kw], wv, acc[ck][jj]);
          }
      }
    }
  }
#pragma unroll
  for (int ck = 0; ck < 4; ++ck)
#pragma unroll
    for (int jj = 0; jj < 4; ++jj)
      xd[((size_t)b * 256 + co0 + cg4 * 4 + ck) * 1024 + (oh0 + i_loc) * 32 + j0 + jj] =
          acc[ck][jj];
}

// ---------------- 2. QKV gemm for coarse stage ----------------
__global__ __launch_bounds__(192) void k_qkv_coarse(const float* __restrict__ xd,
    const float* __restrict__ W, const float* __restrict__ bias,
    float* __restrict__ q, float* __restrict__ k, float* __restrict__ v) {
  int row = blockIdx.x;              // bn*1024 + i
  int bn = row >> 10, i = row & 1023;
  int b = bn >> 2, n = bn & 3;
  __shared__ float t[64];
  if (threadIdx.x < 64)
    t[threadIdx.x] = xd[((size_t)(b * 256 + n * 64 + threadIdx.x)) * 1024 + i];
  __syncthreads();
  int e = threadIdx.x;               // 0..191
  float acc = bias[e];
  const float* wr = W + e * 64;
#pragma unroll
  for (int d = 0; d < 64; ++d) acc = fmaf(t[d], wr[d], acc);
  float* dst = (e < 64) ? q : (e < 128) ? k : v;
  dst[(size_t)row * 64 + (e & 63)] = acc;
}

// ---------------- 3. QKV gemm for topk stage ----------------
__global__ __launch_bounds__(192) void k_qkv_topk(const float* __restrict__ cout,
    const int* __restrict__ idx, const float* __restrict__ W, const float* __restrict__ bias,
    float* __restrict__ q, float* __restrict__ k, float* __restrict__ v) {
  int row = blockIdx.x;              // bn*1024 + t
  int bn = row >> 10, t = row & 1023;
  int b = bn >> 2, n = bn & 3;
  int kk = t >> 2, ab = t & 3;
  int a = ab >> 1, bi = ab & 1;
  __shared__ float tl[64];
  __shared__ int ps;
  if (threadIdx.x == 0) ps = idx[bn * 256 + kk] & 1023;
  __syncthreads();
  int p = ps;
  int sh = (p >> 5) * 2 + a, sw = (p & 31) * 2 + bi;
  if (threadIdx.x < 64)
    tl[threadIdx.x] = cout[((size_t)(b * 256 + n * 64 + threadIdx.x)) * 4096 + sh * 64 + sw];
  __syncthreads();
  int e = threadIdx.x;
  float acc = bias[e];
  const float* wr = W + e * 64;
#pragma unroll
  for (int d = 0; d < 64; ++d) acc = fmaf(tl[d], wr[d], acc);
  float* dst = (e < 64) ? q : (e < 128) ? k : v;
  dst[(size_t)row * 64 + (e & 63)] = acc;
}

// ---------------- 4. attention v3: register-blocked tiled GEMMs ----------------
// Block: 64 K-rows (one bn, one row-tile). 256 threads.
// rowgrp = tid>>4 (4 rows), colgrp = tid&15 (4 cols of j, or 4 dims of d in PV).
// Pass A: online row max/denom over 16 Q-tiles. Pass B: exact p, score, PV.
template <bool SCORE>
__global__ __launch_bounds__(256) void k_attn3(
    const float* __restrict__ Q, const float* __restrict__ K,
    const float* __restrict__ V, float* __restrict__ O,
    float* __restrict__ spart) {
  int bn = blockIdx.x >> 4;
  int it = blockIdx.x & 15;
  int tid = threadIdx.x;
  int rowgrp = tid >> 4;        // 0..15
  int colgrp = tid & 15;        // 0..15
  int i0 = rowgrp * 4;
  int j0 = colgrp * 4;
  const float* qb = Q + (size_t)bn * 65536;
  const float* kb = K + (size_t)bn * 65536;
  const float* vb = V + (size_t)bn * 65536;
  int ibase = it * 64;

  __shared__ float Ks[64][68];   // [d][i] transposed
  __shared__ float QP[64][68];   // Q transposed [d][j], reused as P [j][i]
  __shared__ float Vs[64][68];   // [j][d] natural
  __shared__ float sacc[1024];

  if (SCORE)
    for (int i = tid; i < 1024; i += 256) sacc[i] = 0.f;

  // stage K tile transposed
  {
    int r = tid >> 4, c4 = tid & 15;
#pragma unroll
    for (int p4 = 0; p4 < 4; ++p4) {
      int i = p4 * 16 + r;
      float4 kv = *(const float4*)(kb + (size_t)(ibase + i) * 64 + c4 * 4);
      Ks[c4 * 4 + 0][i] = kv.x;
      Ks[c4 * 4 + 1][i] = kv.y;
      Ks[c4 * 4 + 2][i] = kv.z;
      Ks[c4 * 4 + 3][i] = kv.w;
    }
  }

  float m[4], l[4];
#pragma unroll
  for (int a = 0; a < 4; ++a) { m[a] = -3.0e38f; l[a] = 0.f; }

  // ---- pass A: online max/denom ----
  for (int jt = 0; jt < 16; ++jt) {
    __syncthreads();
    {
      int r = tid >> 4, c4 = tid & 15;
#pragma unroll
      for (int p4 = 0; p4 < 4; ++p4) {
        int j = p4 * 16 + r;
        float4 qv = *(const float4*)(qb + (size_t)(jt * 64 + j) * 64 + c4 * 4);
        QP[c4 * 4 + 0][j] = qv.x;
        QP[c4 * 4 + 1][j] = qv.y;
        QP[c4 * 4 + 2][j] = qv.z;
        QP[c4 * 4 + 3][j] = qv.w;
      }
    }
    __syncthreads();
    float s[4][4];
#pragma unroll
    for (int a = 0; a < 4; ++a)
#pragma unroll
      for (int b = 0; b < 4; ++b) s[a][b] = 0.f;
#pragma unroll 4
    for (int d = 0; d < 64; ++d) {
      float4 kv = *(const float4*)&Ks[d][i0];
      float4 qv = *(const float4*)&QP[d][j0];
      s[0][0] = fmaf(kv.x, qv.x, s[0][0]); s[0][1] = fmaf(kv.x, qv.y, s[0][1]);
      s[0][2] = fmaf(kv.x, qv.z, s[0][2]); s[0][3] = fmaf(kv.x, qv.w, s[0][3]);
      s[1][0] = fmaf(kv.y, qv.x, s[1][0]); s[1][1] = fmaf(kv.y, qv.y, s[1][1]);
      s[1][2] = fmaf(kv.y, qv.z, s[1][2]); s[1][3] = fmaf(kv.y, qv.w, s[1][3]);
      s[2][0] = fmaf(kv.z, qv.x, s[2][0]); s[2][1] = fmaf(kv.z, qv.y, s[2][1]);
      s[2][2] = fmaf(kv.z, qv.z, s[2][2]); s[2][3] = fmaf(kv.z, qv.w, s[2][3]);
      s[3][0] = fmaf(kv.w, qv.x, s[3][0]); s[3][1] = fmaf(kv.w, qv.y, s[3][1]);
      s[3][2] = fmaf(kv.w, qv.z, s[3][2]); s[3][3] = fmaf(kv.w, qv.w, s[3][3]);
    }
#pragma unroll
    for (int a = 0; a < 4; ++a) {
      float tm = fmaxf(fmaxf(s[a][0], s[a][1]), fmaxf(s[a][2], s[a][3]));
#pragma unroll
      for (int off = 1; off <= 8; off <<= 1) tm = fmaxf(tm, __shfl_xor(tm, off, 64));
      float mn = fmaxf(m[a], tm);
      float ts = ((expf(s[a][0] - mn) + expf(s[a][1] - mn)) +
                  expf(s[a][2] - mn)) + expf(s[a][3] - mn);
#pragma unroll
      for (int off = 1; off <= 8; off <<= 1) ts += __shfl_xor(ts, off, 64);
      l[a] = l[a] * expf(m[a] - mn) + ts;
      m[a] = mn;
    }
  }
  float inv[4];
#pragma unroll
  for (int a = 0; a < 4; ++a) inv[a] = 1.f / l[a];

  // ---- pass B: exact p, score, PV ----
  float accO[4][4];
#pragma unroll
  for (int a = 0; a < 4; ++a)
#pragma unroll
    for (int b = 0; b < 4; ++b) accO[a][b] = 0.f;

  for (int jt = 0; jt < 16; ++jt) {
    __syncthreads();
    {
      int r = tid >> 4, c4 = tid & 15;
#pragma unroll
      for (int p4 = 0; p4 < 4; ++p4) {
        int j = p4 * 16 + r;
        float4 qv = *(const float4*)(qb + (size_t)(jt * 64 + j) * 64 + c4 * 4);
        QP[c4 * 4 + 0][j] = qv.x;
        QP[c4 * 4 + 1][j] = qv.y;
        QP[c4 * 4 + 2][j] = qv.z;
        QP[c4 * 4 + 3][j] = qv.w;
        float4 vv = *(const float4*)(vb + (size_t)(jt * 64 + j) * 64 + c4 * 4);
        *(float4*)&Vs[j][c4 * 4] = vv;
      }
    }
    __syncthreads();
    float s[4][4];
#pragma unroll
    for (int a = 0; a < 4; ++a)
#pragma unroll
      for (int b = 0; b < 4; ++b) s[a][b] = 0.f;
#pragma unroll 4
    for (int d = 0; d < 64; ++d) {
      float4 kv = *(const float4*)&Ks[d][i0];
      float4 qv = *(const float4*)&QP[d][j0];
      s[0][0] = fmaf(kv.x, qv.x, s[0][0]); s[0][1] = fmaf(kv.x, qv.y, s[0][1]);
      s[0][2] = fmaf(kv.x, qv.z, s[0][2]); s[0][3] = fmaf(kv.x, qv.w, s[0][3]);
      s[1][0] = fmaf(kv.y, qv.x, s[1][0]); s[1][1] = fmaf(kv.y, qv.y, s[1][1]);
      s[1][2] = fmaf(kv.y, qv.z, s[1][2]); s[1][3] = fmaf(kv.y, qv.w, s[1][3]);
      s[2][0] = fmaf(kv.z, qv.x, s[2][0]); s[2][1] = fmaf(kv.z, qv.y, s[2][1]);
      s[2][2] = fmaf(kv.z, qv.z, s[2][2]); s[2][3] = fmaf(kv.z, qv.w, s[2][3]);
      s[3][0] = fmaf(kv.w, qv.x, s[3][0]); s[3][1] = fmaf(kv.w, qv.y, s[3][1]);
      s[3][2] = fmaf(kv.w, qv.z, s[3][2]); s[3][3] = fmaf(kv.w, qv.w, s[3][3]);
    }
    float p[4][4];
#pragma unroll
    for (int a = 0; a < 4; ++a)
#pragma unroll
      for (int b = 0; b < 4; ++b) p[a][b] = expf(s[a][b] - m[a]) * inv[a];
    if (SCORE) {
#pragma unroll
      for (int b = 0; b < 4; ++b) {
        float cs = ((p[0][b] + p[1][b]) + p[2][b]) + p[3][b];
        atomicAdd(&sacc[jt * 64 + j0 + b], cs);
      }
    }
    __syncthreads();   // all S reads of QP done -> safe to overwrite with P
#pragma unroll
    for (int b = 0; b < 4; ++b)
      *(float4*)&QP[j0 + b][i0] = make_float4(p[0][b], p[1][b], p[2][b], p[3][b]);
    __syncthreads();
    // PV: rows i0..i0+3, dims j0..j0+3 (colgrp reused as d-group)
#pragma unroll 4
    for (int j = 0; j < 64; ++j) {
      float4 pv = *(const float4*)&QP[j][i0];
      float4 vv = *(const float4*)&Vs[j][j0];
      accO[0][0] = fmaf(pv.x, vv.x, accO[0][0]); accO[0][1] = fmaf(pv.x, vv.y, accO[0][1]);
      accO[0][2] = fmaf(pv.x, vv.z, accO[0][2]); accO[0][3] = fmaf(pv.x, vv.w, accO[0][3]);
      accO[1][0] = fmaf(pv.y, vv.x, accO[1][0]); accO[1][1] = fmaf(pv.y, vv.y, accO[1][1]);
      accO[1][2] = fmaf(pv.y, vv.z, accO[1][2]); accO[1][3] = fmaf(pv.y, vv.w, accO[1][3]);
      accO[2][0] = fmaf(pv.z, vv.x, accO[2][0]); accO[2][1] = fmaf(pv.z, vv.y, accO[2][1]);
      accO[2][2] = fmaf(pv.z, vv.z, accO[2][2]); accO[2][3] = fmaf(pv.z, vv.w, accO[2][3]);
      accO[3][0] = fmaf(pv.w, vv.x, accO[3][0]); accO[3][1] = fmaf(pv.w, vv.y, accO[3][1]);
      accO[3][2] = fmaf(pv.w, vv.z, accO[3][2]); accO[3][3] = fmaf(pv.w, vv.w, accO[3][3]);
    }
  }
#pragma unroll
  for (int a = 0; a < 4; ++a) {
    float4 o4 = make_float4(accO[a][0], accO[a][1], accO[a][2], accO[a][3]);
    *(float4*)(O + ((size_t)bn * 1024 + ibase + i0 + a) * 64 + j0) = o4;
  }
  if (SCORE) {
    __syncthreads();
    for (int i = tid; i < 1024; i += 256)
      spart[((size_t)bn * 16 + it) * 1024 + i] = sacc[i];
  }
}

// ---------------- 5. deterministic score reduction (16 partials) ----------------
__global__ __launch_bounds__(256) void k_score_reduce(const float* __restrict__ part,
                                                      float* __restrict__ score) {
  int j = blockIdx.x * 256 + threadIdx.x;   // 0..32767
  int bn = j >> 10, jj = j & 1023;
  float s = 0.f;
  for (int g = 0; g < 16; ++g) s += part[((size_t)bn * 16 + g) * 1024 + jj];
  score[j] = s;
}

// ---------------- 5b. default-init idx ----------------
__global__ __launch_bounds__(256) void k_idx_init(int* __restrict__ idx) {
  int j = blockIdx.x * 256 + threadIdx.x;
  idx[j] = j & 255;
}

// ---------------- 6. top-K by rank ----------------
__global__ __launch_bounds__(1024) void k_topk(const float* __restrict__ score,
                                               int* __restrict__ idxout) {
  int bn = blockIdx.x;
  int t = threadIdx.x;
  __shared__ float s[1024];
  s[t] = score[bn * 1024 + t];
  __syncthreads();
  float my = s[t];
  int rank = 0;
  for (int j = 0; j < 1024; ++j) {
    float o = s[j];
    rank += (o > my) || (o == my && j < t);
  }
  if (rank < 256) idxout[bn * 256 + rank] = t;
}

// ---------------- 7. transposed conv v2: class-split, LDS-tiled ----------------
__global__ __launch_bounds__(256) void k_conv_up2(const float* __restrict__ att,
    const float* __restrict__ wt, const float* __restrict__ bias,
    float* __restrict__ cout) {
  int blk = blockIdx.x;              // ((b*4+cls)*4 + cg)*16 + ip
  int ip = blk & 15;
  int cg = (blk >> 4) & 3;
  int cls = (blk >> 6) & 3;
  int b = blk >> 8;
  int r = cls >> 1, s = cls & 1;
  int i0 = ip * 2;
  int co0 = cg * 64;
  int t = threadIdx.x;
  int cg4 = t >> 4;
  int px = t & 15;
  int i_loc = px >> 3;
  int j0 = (px & 7) << 2;

  __shared__ float xs[16][3][36];
  __shared__ float ws[16][4][64];

  float acc[4][4];
#pragma unroll
  for (int ck = 0; ck < 4; ++ck) {
    float bv = bias[co0 + cg4 * 4 + ck];
#pragma unroll
    for (int jj = 0; jj < 4; ++jj) acc[ck][jj] = bv;
  }
  int rbase = i0 + r;
  const float* ab = att + (size_t)b * 4 * 65536;
  int cs = j0 + s;

  for (int ci0 = 0; ci0 < 256; ci0 += 16) {
    __syncthreads();
    for (int idx = t; idx < 16 * 102; idx += 256) {
      int cl = idx / 102;
      int rem = idx - cl * 102;
      int rho = rem / 34;
      int c = rem - rho * 34;
      int ih = rbase + rho - 1;
      int iw = c - 1;
      int ci = ci0 + cl;
      int n = ci >> 6, d = ci & 63;
      float v = 0.f;
      if ((unsigned)ih < 32u && (unsigned)iw < 32u)
        v = ab[((size_t)n * 1024 + ih * 32 + iw) * 64 + d];
      xs[cl][rho][c] = v;
    }
    for (int idx = t; idx < 16 * 4 * 64; idx += 256) {
      int cl = idx >> 8;
      int tap = (idx >> 6) & 3;
      int c = idx & 63;
      ws[cl][tap][c] = wt[(((size_t)(cls * 4 + tap) * 256) + ci0 + cl) * 256 + co0 + c];
    }
    __syncthreads();
#pragma unroll
    for (int cl = 0; cl < 16; ++cl) {
      float xA[5], xB[5];
#pragma unroll
      for (int u = 0; u < 5; ++u) {
        xA[u] = xs[cl][i_loc + 1][cs + u];
        xB[u] = xs[cl][i_loc][cs + u];
      }
#pragma unroll
      for (int ck = 0; ck < 4; ++ck) {
        int col = cg4 * 4 + ck;
        float wAA = ws[cl][0][col];
        float wAB = ws[cl][1][col];
        float wBA = ws[cl][2][col];
        float wBB = ws[cl][3][col];
#pragma unroll
        for (int jj = 0; jj < 4; ++jj) {
          float a = acc[ck][jj];
          a = fmaf(xA[jj + 1], wAA, a);
          a = fmaf(xA[jj],     wAB, a);
          a = fmaf(xB[jj + 1], wBA, a);
          a = fmaf(xB[jj],     wBB, a);
          acc[ck][jj] = a;
        }
      }
    }
  }
#pragma unroll
  for (int ck = 0; ck < 4; ++ck) {
    int oh = 2 * (i0 + i_loc) + r;
#pragma unroll
    for (int jj = 0; jj < 4; ++jj) {
      int ow = 2 * (j0 + jj) + s;
      cout[((size_t)b * 256 + co0 + cg4 * 4 + ck) * 4096 + oh * 64 + ow] = acc[ck][jj];
    }
  }
}

// ---------------- 8. y = coarse_out + region ----------------
__global__ __launch_bounds__(256) void k_ybuild(const float* __restrict__ cout,
                                                float* __restrict__ y) {
  size_t e = (size_t)blockIdx.x * 256 + threadIdx.x;
  int flat = (int)(e & 4095);
  size_t bc = e >> 12;
  int p = flat >> 2, ab = flat & 3;
  int a = ab >> 1, bi = ab & 1;
  int src = ((p >> 5) * 2 + a) * 64 + (p & 31) * 2 + bi;
  const float* cb = cout + bc * 4096;
  y[e] = cb[flat] + cb[src];
}

// ---------------- 9. scatter-add attended tokens ----------------
__global__ __launch_bounds__(256) void k_scatter(const float* __restrict__ out2,
    const int* __restrict__ idx, float* __restrict__ y) {
  int e = blockIdx.x * 256 + threadIdx.x;
  int d = e & 63;
  int r = e >> 6;
  int ab = r & 3;
  int r2 = r >> 2;
  int kk = r2 & 255;
  int bn = r2 >> 8;
  int b = bn >> 2, n = bn & 3;
  int p = idx[bn * 256 + kk] & 1023;
  int flat = p * 4 + ab;
  int t = kk * 4 + ab;
  y[((size_t)(b * 256 + n * 64 + d)) * 4096 + flat] +=
      out2[((size_t)bn * 1024 + t) * 64 + d];
}

// ---------------- 10. depthwise 3x3 + BN + relu6 ----------------
__global__ __launch_bounds__(256) void k_dw(const float* __restrict__ y,
    const float* __restrict__ w, const float* __restrict__ g, const float* __restrict__ bb,
    const float* __restrict__ mm, const float* __restrict__ vv, float* __restrict__ t1) {
  size_t e = (size_t)blockIdx.x * 256 + threadIdx.x;
  int pix = (int)(e & 4095);
  int c = (int)((e >> 12) & 255);
  int oh = pix >> 6, ow = pix & 63;
  const float* yb = y + (e - pix);
  float acc = 0.f;
#pragma unroll
  for (int kh = 0; kh < 3; ++kh) {
    int ih = oh - 1 + kh;
    if ((unsigned)ih >= 64u) continue;
#pragma unroll
    for (int kw = 0; kw < 3; ++kw) {
      int iw = ow - 1 + kw;
      if ((unsigned)iw >= 64u) continue;
      acc = fmaf(yb[ih * 64 + iw], w[c * 9 + kh * 3 + kw], acc);
    }
  }
  float s = g[c] * rsqrtf(vv[c] + 1e-5f);
  float val = acc * s + (bb[c] - mm[c] * s);
  t1[e] = fminf(fmaxf(val, 0.f), 6.f);
}

// ---------------- 11. pointwise 1x1 + BN + relu6 -> fp32 out ----------------
__global__ __launch_bounds__(256) void k_pw(const float* __restrict__ t1,
    const float* __restrict__ w, const float* __restrict__ g, const float* __restrict__ bb,
    const float* __restrict__ mm, const float* __restrict__ vv, float* __restrict__ out) {
  int blk = blockIdx.x;
  int tile = blk & 3;
  int co = (blk >> 2) & 255;
  int b = blk >> 10;
  __shared__ float wl[256];
  wl[threadIdx.x] = w[co * 256 + threadIdx.x];
  __syncthreads();
  int pix0 = tile * 1024 + threadIdx.x * 4;
  const float4* tb = (const float4*)(t1 + (size_t)b * 256 * 4096 + pix0);
  float ax = 0.f, ay = 0.f, az = 0.f, aw = 0.f;
  for (int ci = 0; ci < 256; ++ci) {
    float4 tv = tb[(size_t)ci * 1024];
    float wv = wl[ci];
    ax = fmaf(tv.x, wv, ax);
    ay = fmaf(tv.y, wv, ay);
    az = fmaf(tv.z, wv, az);
    aw = fmaf(tv.w, wv, aw);
  }
  float s = g[co] * rsqrtf(vv[co] + 1e-5f);
  float bias = bb[co] - mm[co] * s;
  float4 o4;
  o4.x = fminf(fmaxf(ax * s + bias, 0.f), 6.f);
  o4.y = fminf(fmaxf(ay * s + bias, 0.f), 6.f);
  o4.z = fminf(fmaxf(az * s + bias, 0.f), 6.f);
  o4.w = fminf(fmaxf(aw * s + bias, 0.f), 6.f);
  *(float4*)(out + ((size_t)(b * 256 + co)) * 4096 + pix0) = o4;
}

// ---------------- launcher ----------------
extern "C" void kernel_launch(void* const* d_in, const int* in_sizes, int n_in,
                              void* d_out, int out_size, void* d_ws, size_t ws_size,
                              hipStream_t stream) {
  if (ws_size < WS_FLOATS * sizeof(float)) return;

  const float* x      = (const float*)d_in[0];
  const float* down_w = (const float*)d_in[1];
  const float* down_b = (const float*)d_in[2];
  const float* up_w   = (const float*)d_in[3];
  const float* up_b   = (const float*)d_in[4];
  const float* cqkv_w = (const float*)d_in[5];
  const float* cqkv_b = (const float*)d_in[6];
  const float* tqkv_w = (const float*)d_in[7];
  const float* tqkv_b = (const float*)d_in[8];
  const float* dww    = (const float*)d_in[9];
  const float* bn1g   = (const float*)d_in[10];
  const float* bn1b   = (const float*)d_in[11];
  const float* bn1m   = (const float*)d_in[12];
  const float* bn1v   = (const float*)d_in[13];
  const float* pww    = (const float*)d_in[14];
  const float* bn2g   = (const float*)d_in[15];
  const float* bn2b   = (const float*)d_in[16];
  const float* bn2m   = (const float*)d_in[17];
  const float* bn2v   = (const float*)d_in[18];

  float* ws    = (float*)d_ws;
  float* xd    = ws + OFF_XD;
  float* q     = ws + OFF_Q;
  float* k     = ws + OFF_K;
  float* v     = ws + OFF_V;
  float* att   = ws + OFF_ATT;
  float* spart = ws + OFF_SPART;
  float* score = ws + OFF_SCORE;
  int*   idx   = (int*)(ws + OFF_IDX);
  float* cout  = ws + OFF_COUT;
  float* y     = ws + OFF_Y;
  float* t1    = ws + OFF_T1;
  float* dwt   = ws + OFF_SPART;   // alias: spart dead until k_attn3<true>
  float* wt    = ws + OFF_XD;      // alias: xd dead after k_qkv_coarse

  k_wt_dn<<<4096, 256, 0, stream>>>(down_w, dwt);
  k_conv_down2<<<512, 256, 0, stream>>>(x, dwt, down_b, xd);
  k_qkv_coarse<<<32768, 192, 0, stream>>>(xd, cqkv_w, cqkv_b, q, k, v);
  k_wt_up<<<4096, 256, 0, stream>>>(up_w, wt);          // overwrites xd region
  k_attn3<true><<<512, 256, 0, stream>>>(q, k, v, att, spart);  // overwrites dwt
  k_score_reduce<<<128, 256, 0, stream>>>(spart, score);
  k_idx_init<<<32, 256, 0, stream>>>(idx);
  k_topk<<<32, 1024, 0, stream>>>(score, idx);
  k_conv_up2<<<2048, 256, 0, stream>>>(att, wt, up_b, cout);
  k_qkv_topk<<<32768, 192, 0, stream>>>(cout, idx, tqkv_w, tqkv_b, q, k, v);
  k_attn3<false><<<512, 256, 0, stream>>>(q, k, v, att, spart);
  k_ybuild<<<32768, 256, 0, stream>>>(cout, y);
  k_scatter<<<8192, 256, 0, stream>>>(att, idx, y);
  k_dw<<<32768, 256, 0, stream>>>(y, dww, bn1g, bn1b, bn1m, bn1v, t1);
  k_pw<<<8192, 256, 0, stream>>>(t1, pww, bn2g, bn2b, bn2m, bn2v, (float*)d_out);
}

// Round 8
// 1802.589 us; speedup vs baseline: 14.1267x; 1.1813x over previous
//
#include <hip/hip_runtime.h>
#include <hip/hip_bf16.h>

// ---------------- workspace layout (float offsets) ----------------
// xdT  [32,1024,64]       q/k/v [32,1024,64]      att  [32,1024,64]
// spart[32,16,1024] (+ attT [32,64,1024] at +2M)  score [32,1024]   idx [32,256]
// cout [8,256,64,64]      y     [8,256,64,64]     t1   [8,256,64,64]
// aliases: wt -> xdT region (dead after k_qkv_coarse); dwt -> spart region
//          attT -> spart region +2M; coutT -> t1 region (dead until k_dw)
constexpr size_t OFF_XD    = 0;
constexpr size_t OFF_Q     = 2097152;
constexpr size_t OFF_K     = 4194304;
constexpr size_t OFF_V     = 6291456;
constexpr size_t OFF_ATT   = 8388608;
constexpr size_t OFF_SPART = 10485760;
constexpr size_t OFF_SCORE = 14680064;
constexpr size_t OFF_IDX   = 14712832;
constexpr size_t OFF_COUT  = 14721024;
constexpr size_t OFF_Y     = 23109632;
constexpr size_t OFF_T1    = 31498240;
constexpr size_t WS_FLOATS = 39886848;

// ---------------- 0a. transpose down_w [co][ci][kh][kw] -> dwt [ci][kk][co] ----
__global__ __launch_bounds__(256) void k_wt_dn(const float* __restrict__ w,
                                               float* __restrict__ dwt) {
  int idx = blockIdx.x * 256 + threadIdx.x;   // 1,048,576
  int co = idx & 255;
  int kk = (idx >> 8) & 15;
  int ci = idx >> 12;
  dwt[((size_t)(ci * 16 + kk)) * 256 + co] = w[((size_t)(co * 256 + ci)) * 16 + kk];
}

// ---------------- 0b. transpose up_w [ci][co][kh][kw] -> wt [cls][tap][ci][co] --
__global__ __launch_bounds__(256) void k_wt_up(const float* __restrict__ w,
                                               float* __restrict__ wt) {
  int idx = blockIdx.x * 256 + threadIdx.x;   // 1,048,576
  int co = idx & 255;
  int ci = (idx >> 8) & 255;
  int tp = idx >> 16;                         // 0..15
  int cls = tp >> 2, tap = tp & 3;
  int r = cls >> 1, s = cls & 1;
  int kh = (tap < 2) ? (r ? 0 : 1) : (r ? 2 : 3);
  int kw = ((tap & 1) == 0) ? (s ? 0 : 1) : (s ? 2 : 3);
  wt[idx] = w[((size_t)(ci * 256 + co)) * 16 + kh * 4 + kw];
}

// ---------------- 1. down conv v3: stride-66 xs (conflict-free), float2/float4 --
__global__ __launch_bounds__(256) void k_conv_down3(const float* __restrict__ x,
    const float* __restrict__ dwt, const float* __restrict__ bias,
    float* __restrict__ xdT) {
  int blk = blockIdx.x;            // ((b*4 + cg)*16 + ihp)
  int ihp = blk & 15;
  int cg = (blk >> 4) & 3;
  int b = blk >> 6;
  int oh0 = ihp * 2;
  int co0 = cg * 64;
  int t = threadIdx.x;
  int cg4 = t >> 4;                // 16 co-groups of 4
  int px = t & 15;
  int i_loc = px >> 3;             // 0..1 (oh row)
  int j0 = (px & 7) << 2;          // 0..28 (ow)

  __shared__ float xs[4][6][66];   // stride 66: i_loc bank shift=4 -> 2-way (free)
  __shared__ float ws[4][16][64];

  float acc[4][4];
#pragma unroll
  for (int ck = 0; ck < 4; ++ck) {
    float bv = bias[co0 + cg4 * 4 + ck];
#pragma unroll
    for (int jj = 0; jj < 4; ++jj) acc[ck][jj] = bv;
  }
  const float* xb = x + (size_t)b * 256 * 4096;

  for (int ci0 = 0; ci0 < 256; ci0 += 4) {
    __syncthreads();
    for (int idx = t; idx < 4 * 6 * 66; idx += 256) {
      int cl = idx / 396;
      int rem = idx - cl * 396;
      int row = rem / 66;
      int col = rem - row * 66;
      int ih = oh0 * 2 - 1 + row;
      int iw = col - 1;
      float v = 0.f;
      if ((unsigned)ih < 64u && (unsigned)iw < 64u)
        v = xb[(size_t)(ci0 + cl) * 4096 + ih * 64 + iw];
      xs[cl][row][col] = v;
    }
    for (int idx = t; idx < 4 * 16 * 64; idx += 256) {
      int cl = idx >> 10;
      int kk = (idx >> 6) & 15;
      int c = idx & 63;
      ws[cl][kk][c] = dwt[((size_t)(ci0 + cl) * 16 + kk) * 256 + co0 + c];
    }
    __syncthreads();
#pragma unroll
    for (int cl = 0; cl < 4; ++cl) {
      float xr[4][10];
#pragma unroll
      for (int rr = 0; rr < 4; ++rr) {
        const float* rp = &xs[cl][2 * i_loc + rr][2 * j0];
#pragma unroll
        for (int kp = 0; kp < 5; ++kp) {
          float2 p = *(const float2*)(rp + 2 * kp);
          xr[rr][2 * kp] = p.x;
          xr[rr][2 * kp + 1] = p.y;
        }
      }
#pragma unroll
      for (int kh = 0; kh < 4; ++kh)
#pragma unroll
        for (int kw = 0; kw < 4; ++kw) {
          float4 wq = *(const float4*)&ws[cl][kh * 4 + kw][cg4 * 4];
#pragma unroll
          for (int jj = 0; jj < 4; ++jj) {
            float xv = xr[kh][2 * jj + kw];
            acc[0][jj] = fmaf(xv, wq.x, acc[0][jj]);
            acc[1][jj] = fmaf(xv, wq.y, acc[1][jj]);
            acc[2][jj] = fmaf(xv, wq.z, acc[2][jj]);
            acc[3][jj] = fmaf(xv, wq.w, acc[3][jj]);
          }
        }
    }
  }
  int bn = b * 4 + cg;
  int pixr = (oh0 + i_loc) * 32 + j0;
#pragma unroll
  for (int jj = 0; jj < 4; ++jj) {
    float4 o4 = make_float4(acc[0][jj], acc[1][jj], acc[2][jj], acc[3][jj]);
    *(float4*)(xdT + ((size_t)bn * 1024 + pixr + jj) * 64 + cg4 * 4) = o4;
  }
}

// ---------------- 2. QKV gemm coarse: coalesced xdT staging ----------------
__global__ __launch_bounds__(192) void k_qkv_coarse(const float* __restrict__ xdT,
    const float* __restrict__ W, const float* __restrict__ bias,
    float* __restrict__ q, float* __restrict__ k, float* __restrict__ v) {
  int row = blockIdx.x;              // bn*1024 + i
  int bn = row >> 10, i = row & 1023;
  __shared__ float t[64];
  if (threadIdx.x < 64)
    t[threadIdx.x] = xdT[((size_t)bn * 1024 + i) * 64 + threadIdx.x];
  __syncthreads();
  int e = threadIdx.x;               // 0..191
  float acc = bias[e];
  const float* wr = W + e * 64;
#pragma unroll
  for (int d = 0; d < 64; ++d) acc = fmaf(t[d], wr[d], acc);
  float* dst = (e < 64) ? q : (e < 128) ? k : v;
  dst[(size_t)row * 64 + (e & 63)] = acc;
}

// ---------------- 3. QKV gemm topk: coalesced coutT staging ----------------
__global__ __launch_bounds__(192) void k_qkv_topk(const float* __restrict__ coutT,
    const int* __restrict__ idx, const float* __restrict__ W, const float* __restrict__ bias,
    float* __restrict__ q, float* __restrict__ k, float* __restrict__ v) {
  int row = blockIdx.x;              // bn*1024 + t
  int bn = row >> 10, t = row & 1023;
  int kk = t >> 2, ab = t & 3;
  int a = ab >> 1, bi = ab & 1;
  __shared__ float tl[64];
  __shared__ int ps;
  if (threadIdx.x == 0) ps = idx[bn * 256 + kk] & 1023;
  __syncthreads();
  int p = ps;
  int sh = (p >> 5) * 2 + a, sw = (p & 31) * 2 + bi;
  if (threadIdx.x < 64)
    tl[threadIdx.x] = coutT[((size_t)bn * 4096 + sh * 64 + sw) * 64 + threadIdx.x];
  __syncthreads();
  int e = threadIdx.x;
  float acc = bias[e];
  const float* wr = W + e * 64;
#pragma unroll
  for (int d = 0; d < 64; ++d) acc = fmaf(tl[d], wr[d], acc);
  float* dst = (e < 64) ? q : (e < 128) ? k : v;
  dst[(size_t)row * 64 + (e & 63)] = acc;
}

// ---------------- 4. attention v3 (+ attT transposed output when SCORE) --------
template <bool SCORE>
__global__ __launch_bounds__(256) void k_attn3(
    const float* __restrict__ Q, const float* __restrict__ K,
    const float* __restrict__ V, float* __restrict__ O,
    float* __restrict__ spart, float* __restrict__ attT) {
  int bn = blockIdx.x >> 4;
  int it = blockIdx.x & 15;
  int tid = threadIdx.x;
  int rowgrp = tid >> 4;        // 0..15
  int colgrp = tid & 15;        // 0..15
  int i0 = rowgrp * 4;
  int j0 = colgrp * 4;
  const float* qb = Q + (size_t)bn * 65536;
  const float* kb = K + (size_t)bn * 65536;
  const float* vb = V + (size_t)bn * 65536;
  int ibase = it * 64;

  __shared__ float Ks[64][68];   // [d][i] transposed
  __shared__ float QP[64][68];   // Q transposed [d][j], reused as P [j][i]
  __shared__ float Vs[64][68];   // [j][d] natural
  __shared__ float sacc[1024];

  if (SCORE)
    for (int i = tid; i < 1024; i += 256) sacc[i] = 0.f;

  {
    int r = tid >> 4, c4 = tid & 15;
#pragma unroll
    for (int p4 = 0; p4 < 4; ++p4) {
      int i = p4 * 16 + r;
      float4 kv = *(const float4*)(kb + (size_t)(ibase + i) * 64 + c4 * 4);
      Ks[c4 * 4 + 0][i] = kv.x;
      Ks[c4 * 4 + 1][i] = kv.y;
      Ks[c4 * 4 + 2][i] = kv.z;
      Ks[c4 * 4 + 3][i] = kv.w;
    }
  }

  float m[4], l[4];
#pragma unroll
  for (int a = 0; a < 4; ++a) { m[a] = -3.0e38f; l[a] = 0.f; }

  for (int jt = 0; jt < 16; ++jt) {
    __syncthreads();
    {
      int r = tid >> 4, c4 = tid & 15;
#pragma unroll
      for (int p4 = 0; p4 < 4; ++p4) {
        int j = p4 * 16 + r;
        float4 qv = *(const float4*)(qb + (size_t)(jt * 64 + j) * 64 + c4 * 4);
        QP[c4 * 4 + 0][j] = qv.x;
        QP[c4 * 4 + 1][j] = qv.y;
        QP[c4 * 4 + 2][j] = qv.z;
        QP[c4 * 4 + 3][j] = qv.w;
      }
    }
    __syncthreads();
    float s[4][4];
#pragma unroll
    for (int a = 0; a < 4; ++a)
#pragma unroll
      for (int b = 0; b < 4; ++b) s[a][b] = 0.f;
#pragma unroll 4
    for (int d = 0; d < 64; ++d) {
      float4 kv = *(const float4*)&Ks[d][i0];
      float4 qv = *(const float4*)&QP[d][j0];
      s[0][0] = fmaf(kv.x, qv.x, s[0][0]); s[0][1] = fmaf(kv.x, qv.y, s[0][1]);
      s[0][2] = fmaf(kv.x, qv.z, s[0][2]); s[0][3] = fmaf(kv.x, qv.w, s[0][3]);
      s[1][0] = fmaf(kv.y, qv.x, s[1][0]); s[1][1] = fmaf(kv.y, qv.y, s[1][1]);
      s[1][2] = fmaf(kv.y, qv.z, s[1][2]); s[1][3] = fmaf(kv.y, qv.w, s[1][3]);
      s[2][0] = fmaf(kv.z, qv.x, s[2][0]); s[2][1] = fmaf(kv.z, qv.y, s[2][1]);
      s[2][2] = fmaf(kv.z, qv.z, s[2][2]); s[2][3] = fmaf(kv.z, qv.w, s[2][3]);
      s[3][0] = fmaf(kv.w, qv.x, s[3][0]); s[3][1] = fmaf(kv.w, qv.y, s[3][1]);
      s[3][2] = fmaf(kv.w, qv.z, s[3][2]); s[3][3] = fmaf(kv.w, qv.w, s[3][3]);
    }
#pragma unroll
    for (int a = 0; a < 4; ++a) {
      float tm = fmaxf(fmaxf(s[a][0], s[a][1]), fmaxf(s[a][2], s[a][3]));
#pragma unroll
      for (int off = 1; off <= 8; off <<= 1) tm = fmaxf(tm, __shfl_xor(tm, off, 64));
      float mn = fmaxf(m[a], tm);
      float ts = ((expf(s[a][0] - mn) + expf(s[a][1] - mn)) +
                  expf(s[a][2] - mn)) + expf(s[a][3] - mn);
#pragma unroll
      for (int off = 1; off <= 8; off <<= 1) ts += __shfl_xor(ts, off, 64);
      l[a] = l[a] * expf(m[a] - mn) + ts;
      m[a] = mn;
    }
  }
  float inv[4];
#pragma unroll
  for (int a = 0; a < 4; ++a) inv[a] = 1.f / l[a];

  float accO[4][4];
#pragma unroll
  for (int a = 0; a < 4; ++a)
#pragma unroll
    for (int b = 0; b < 4; ++b) accO[a][b] = 0.f;

  for (int jt = 0; jt < 16; ++jt) {
    __syncthreads();
    {
      int r = tid >> 4, c4 = tid & 15;
#pragma unroll
      for (int p4 = 0; p4 < 4; ++p4) {
        int j = p4 * 16 + r;
        float4 qv = *(const float4*)(qb + (size_t)(jt * 64 + j) * 64 + c4 * 4);
        QP[c4 * 4 + 0][j] = qv.x;
        QP[c4 * 4 + 1][j] = qv.y;
        QP[c4 * 4 + 2][j] = qv.z;
        QP[c4 * 4 + 3][j] = qv.w;
        float4 vv = *(const float4*)(vb + (size_t)(jt * 64 + j) * 64 + c4 * 4);
        *(float4*)&Vs[j][c4 * 4] = vv;
      }
    }
    __syncthreads();
    float s[4][4];
#pragma unroll
    for (int a = 0; a < 4; ++a)
#pragma unroll
      for (int b = 0; b < 4; ++b) s[a][b] = 0.f;
#pragma unroll 4
    for (int d = 0; d < 64; ++d) {
      float4 kv = *(const float4*)&Ks[d][i0];
      float4 qv = *(const float4*)&QP[d][j0];
      s[0][0] = fmaf(kv.x, qv.x, s[0][0]); s[0][1] = fmaf(kv.x, qv.y, s[0][1]);
      s[0][2] = fmaf(kv.x, qv.z, s[0][2]); s[0][3] = fmaf(kv.x, qv.w, s[0][3]);
      s[1][0] = fmaf(kv.y, qv.x, s[1][0]); s[1][1] = fmaf(kv.y, qv.y, s[1][1]);
      s[1][2] = fmaf(kv.y, qv.z, s[1][2]); s[1][3] = fmaf(kv.y, qv.w, s[1][3]);
      s[2][0] = fmaf(kv.z, qv.x, s[2][0]); s[2][1] = fmaf(kv.z, qv.y, s[2][1]);
      s[2][2] = fmaf(kv.z, qv.z, s[2][2]); s[2][3] = fmaf(kv.z, qv.w, s[2][3]);
      s[3][0] = fmaf(kv.w, qv.x, s[3][0]); s[3][1] = fmaf(kv.w, qv.y, s[3][1]);
      s[3][2] = fmaf(kv.w, qv.z, s[3][2]); s[3][3] = fmaf(kv.w, qv.w, s[3][3]);
    }
    float p[4][4];
#pragma unroll
    for (int a = 0; a < 4; ++a)
#pragma unroll
      for (int b = 0; b < 4; ++b) p[a][b] = expf(s[a][b] - m[a]) * inv[a];
    if (SCORE) {
#pragma unroll
      for (int b = 0; b < 4; ++b) {
        float cs = ((p[0][b] + p[1][b]) + p[2][b]) + p[3][b];
        atomicAdd(&sacc[jt * 64 + j0 + b], cs);
      }
    }
    __syncthreads();
#pragma unroll
    for (int b = 0; b < 4; ++b)
      *(float4*)&QP[j0 + b][i0] = make_float4(p[0][b], p[1][b], p[2][b], p[3][b]);
    __syncthreads();
#pragma unroll 4
    for (int j = 0; j < 64; ++j) {
      float4 pv = *(const float4*)&QP[j][i0];
      float4 vv = *(const float4*)&Vs[j][j0];
      accO[0][0] = fmaf(pv.x, vv.x, accO[0][0]); accO[0][1] = fmaf(pv.x, vv.y, accO[0][1]);
      accO[0][2] = fmaf(pv.x, vv.z, accO[0][2]); accO[0][3] = fmaf(pv.x, vv.w, accO[0][3]);
      accO[1][0] = fmaf(pv.y, vv.x, accO[1][0]); accO[1][1] = fmaf(pv.y, vv.y, accO[1][1]);
      accO[1][2] = fmaf(pv.y, vv.z, accO[1][2]); accO[1][3] = fmaf(pv.y, vv.w, accO[1][3]);
      accO[2][0] = fmaf(pv.z, vv.x, accO[2][0]); accO[2][1] = fmaf(pv.z, vv.y, accO[2][1]);
      accO[2][2] = fmaf(pv.z, vv.z, accO[2][2]); accO[2][3] = fmaf(pv.z, vv.w, accO[2][3]);
      accO[3][0] = fmaf(pv.w, vv.x, accO[3][0]); accO[3][1] = fmaf(pv.w, vv.y, accO[3][1]);
      accO[3][2] = fmaf(pv.w, vv.z, accO[3][2]); accO[3][3] = fmaf(pv.w, vv.w, accO[3][3]);
    }
  }
#pragma unroll
  for (int a = 0; a < 4; ++a) {
    float4 o4 = make_float4(accO[a][0], accO[a][1], accO[a][2], accO[a][3]);
    *(float4*)(O + ((size_t)bn * 1024 + ibase + i0 + a) * 64 + j0) = o4;
  }
  if (SCORE) {
    // transposed copy for conv_up staging: attT[bn][d][i]
#pragma unroll
    for (int a = 0; a < 4; ++a)
#pragma unroll
      for (int b = 0; b < 4; ++b)
        attT[((size_t)bn * 64 + j0 + b) * 1024 + ibase + i0 + a] = accO[a][b];
    __syncthreads();
    for (int i = tid; i < 1024; i += 256)
      spart[((size_t)bn * 16 + it) * 1024 + i] = sacc[i];
  }
}

// ---------------- 5. deterministic score reduction (16 partials) ----------------
__global__ __launch_bounds__(256) void k_score_reduce(const float* __restrict__ part,
                                                      float* __restrict__ score) {
  int j = blockIdx.x * 256 + threadIdx.x;   // 0..32767
  int bn = j >> 10, jj = j & 1023;
  float s = 0.f;
  for (int g = 0; g < 16; ++g) s += part[((size_t)bn * 16 + g) * 1024 + jj];
  score[j] = s;
}

// ---------------- 5b. default-init idx ----------------
__global__ __launch_bounds__(256) void k_idx_init(int* __restrict__ idx) {
  int j = blockIdx.x * 256 + threadIdx.x;
  idx[j] = j & 255;
}

// ---------------- 6. top-K by rank ----------------
__global__ __launch_bounds__(1024) void k_topk(const float* __restrict__ score,
                                               int* __restrict__ idxout) {
  int bn = blockIdx.x;
  int t = threadIdx.x;
  __shared__ float s[1024];
  s[t] = score[bn * 1024 + t];
  __syncthreads();
  float my = s[t];
  int rank = 0;
  for (int j = 0; j < 1024; ++j) {
    float o = s[j];
    rank += (o > my) || (o == my && j < t);
  }
  if (rank < 256) idxout[bn * 256 + rank] = t;
}

// ---------------- 7. transposed conv v3: attT staging, vectorized LDS ----------
__global__ __launch_bounds__(256) void k_conv_up3(const float* __restrict__ attT,
    const float* __restrict__ wt, const float* __restrict__ bias,
    float* __restrict__ cout, float* __restrict__ coutT) {
  int blk = blockIdx.x;              // ((b*4+cls)*4 + cg)*16 + ip
  int ip = blk & 15;
  int cg = (blk >> 4) & 3;
  int cls = (blk >> 6) & 3;
  int b = blk >> 8;
  int r = cls >> 1, s = cls & 1;
  int i0 = ip * 2;
  int co0 = cg * 64;
  int t = threadIdx.x;
  int cg4 = t >> 4;
  int px = t & 15;
  int i_loc = px >> 3;
  int j0 = (px & 7) << 2;

  __shared__ float xs[16][3][36];   // s-shifted: read base j0 (float4-aligned)
  __shared__ float ws[16][4][64];

  float acc[4][4];
#pragma unroll
  for (int ck = 0; ck < 4; ++ck) {
    float bv = bias[co0 + cg4 * 4 + ck];
#pragma unroll
    for (int jj = 0; jj < 4; ++jj) acc[ck][jj] = bv;
  }
  int rbase = i0 + r;
  const float* ab = attT + (size_t)b * 4 * 65536;

  for (int ci0 = 0; ci0 < 256; ci0 += 16) {
    __syncthreads();
    for (int idx = t; idx < 16 * 99; idx += 256) {
      int cl = idx / 99;
      int rem = idx - cl * 99;
      int rho = rem / 33;
      int c = rem - rho * 33;
      int ih = rbase + rho - 1;
      int iw = c - 1 + s;
      int ci = ci0 + cl;
      int n = ci >> 6, d = ci & 63;
      float v = 0.f;
      if ((unsigned)ih < 32u && (unsigned)iw < 32u)
        v = ab[((size_t)n * 64 + d) * 1024 + ih * 32 + iw];   // coalesced in c
      xs[cl][rho][c] = v;
    }
    for (int idx = t; idx < 16 * 4 * 64; idx += 256) {
      int cl = idx >> 8;
      int tap = (idx >> 6) & 3;
      int c = idx & 63;
      ws[cl][tap][c] = wt[(((size_t)(cls * 4 + tap) * 256) + ci0 + cl) * 256 + co0 + c];
    }
    __syncthreads();
#pragma unroll
    for (int cl = 0; cl < 16; ++cl) {
      float4 a4 = *(const float4*)&xs[cl][i_loc + 1][j0];
      float a4e = xs[cl][i_loc + 1][j0 + 4];
      float4 b4 = *(const float4*)&xs[cl][i_loc][j0];
      float b4e = xs[cl][i_loc][j0 + 4];
      float xA[5] = {a4.x, a4.y, a4.z, a4.w, a4e};
      float xB[5] = {b4.x, b4.y, b4.z, b4.w, b4e};
      float4 w0 = *(const float4*)&ws[cl][0][cg4 * 4];
      float4 w1 = *(const float4*)&ws[cl][1][cg4 * 4];
      float4 w2 = *(const float4*)&ws[cl][2][cg4 * 4];
      float4 w3 = *(const float4*)&ws[cl][3][cg4 * 4];
      const float* w0p = (const float*)&w0;
      const float* w1p = (const float*)&w1;
      const float* w2p = (const float*)&w2;
      const float* w3p = (const float*)&w3;
#pragma unroll
      for (int ck = 0; ck < 4; ++ck) {
        float wAA = w0p[ck], wAB = w1p[ck], wBA = w2p[ck], wBB = w3p[ck];
#pragma unroll
        for (int jj = 0; jj < 4; ++jj) {
          float a = acc[ck][jj];
          a = fmaf(xA[jj + 1], wAA, a);
          a = fmaf(xA[jj],     wAB, a);
          a = fmaf(xB[jj + 1], wBA, a);
          a = fmaf(xB[jj],     wBB, a);
          acc[ck][jj] = a;
        }
      }
    }
  }
  int oh = 2 * (i0 + i_loc) + r;
#pragma unroll
  for (int ck = 0; ck < 4; ++ck) {
#pragma unroll
    for (int jj = 0; jj < 4; ++jj) {
      int ow = 2 * (j0 + jj) + s;
      cout[((size_t)b * 256 + co0 + cg4 * 4 + ck) * 4096 + oh * 64 + ow] = acc[ck][jj];
    }
  }
  int bn = b * 4 + cg;
#pragma unroll
  for (int jj = 0; jj < 4; ++jj) {
    int ow = 2 * (j0 + jj) + s;
    float4 o4 = make_float4(acc[0][jj], acc[1][jj], acc[2][jj], acc[3][jj]);
    *(float4*)(coutT + ((size_t)bn * 4096 + oh * 64 + ow) * 64 + cg4 * 4) = o4;
  }
}

// ---------------- 8. y = coarse_out + region ----------------
__global__ __launch_bounds__(256) void k_ybuild(const float* __restrict__ cout,
                                                float* __restrict__ y) {
  size_t e = (size_t)blockIdx.x * 256 + threadIdx.x;
  int flat = (int)(e & 4095);
  size_t bc = e >> 12;
  int p = flat >> 2, ab = flat & 3;
  int a = ab >> 1, bi = ab & 1;
  int src = ((p >> 5) * 2 + a) * 64 + (p & 31) * 2 + bi;
  const float* cb = cout + bc * 4096;
  y[e] = cb[flat] + cb[src];
}

// ---------------- 9. scatter-add attended tokens ----------------
__global__ __launch_bounds__(256) void k_scatter(const float* __restrict__ out2,
    const int* __restrict__ idx, float* __restrict__ y) {
  int e = blockIdx.x * 256 + threadIdx.x;
  int d = e & 63;
  int r = e >> 6;
  int ab = r & 3;
  int r2 = r >> 2;
  int kk = r2 & 255;
  int bn = r2 >> 8;
  int b = bn >> 2, n = bn & 3;
  int p = idx[bn * 256 + kk] & 1023;
  int flat = p * 4 + ab;
  int t = kk * 4 + ab;
  y[((size_t)(b * 256 + n * 64 + d)) * 4096 + flat] +=
      out2[((size_t)bn * 1024 + t) * 64 + d];
}

// ---------------- 10. depthwise 3x3 + BN + relu6 ----------------
__global__ __launch_bounds__(256) void k_dw(const float* __restrict__ y,
    const float* __restrict__ w, const float* __restrict__ g, const float* __restrict__ bb,
    const float* __restrict__ mm, const float* __restrict__ vv, float* __restrict__ t1) {
  size_t e = (size_t)blockIdx.x * 256 + threadIdx.x;
  int pix = (int)(e & 4095);
  int c = (int)((e >> 12) & 255);
  int oh = pix >> 6, ow = pix & 63;
  const float* yb = y + (e - pix);
  float acc = 0.f;
#pragma unroll
  for (int kh = 0; kh < 3; ++kh) {
    int ih = oh - 1 + kh;
    if ((unsigned)ih >= 64u) continue;
#pragma unroll
    for (int kw = 0; kw < 3; ++kw) {
      int iw = ow - 1 + kw;
      if ((unsigned)iw >= 64u) continue;
      acc = fmaf(yb[ih * 64 + iw], w[c * 9 + kh * 3 + kw], acc);
    }
  }
  float s = g[c] * rsqrtf(vv[c] + 1e-5f);
  float val = acc * s + (bb[c] - mm[c] * s);
  t1[e] = fminf(fmaxf(val, 0.f), 6.f);
}

// ---------------- 11. pointwise v2: 4 co per block, 16 FMA per 16B load --------
__global__ __launch_bounds__(256) void k_pw2(const float* __restrict__ t1,
    const float* __restrict__ w, const float* __restrict__ g, const float* __restrict__ bb,
    const float* __restrict__ mm, const float* __restrict__ vv, float* __restrict__ out) {
  int blk = blockIdx.x;              // (b*64 + cog)*4 + tile
  int tile = blk & 3;
  int cog = (blk >> 2) & 63;
  int b = blk >> 8;
  int co0 = cog * 4;
  int t = threadIdx.x;
  __shared__ float wl[256][4];
  for (int idx = t; idx < 1024; idx += 256) {
    int cof = idx >> 8;
    int ci = idx & 255;
    wl[ci][cof] = w[(co0 + cof) * 256 + ci];
  }
  __syncthreads();
  int px0 = tile * 1024 + t * 4;
  const float* tb = t1 + (size_t)b * 256 * 4096 + px0;
  float acc[4][4];
#pragma unroll
  for (int a = 0; a < 4; ++a)
#pragma unroll
    for (int jj = 0; jj < 4; ++jj) acc[a][jj] = 0.f;
  for (int ci = 0; ci < 256; ++ci) {
    float4 tv = *(const float4*)(tb + (size_t)ci * 4096);
    float4 wv = *(const float4*)&wl[ci][0];
    acc[0][0] = fmaf(tv.x, wv.x, acc[0][0]); acc[0][1] = fmaf(tv.y, wv.x, acc[0][1]);
    acc[0][2] = fmaf(tv.z, wv.x, acc[0][2]); acc[0][3] = fmaf(tv.w, wv.x, acc[0][3]);
    acc[1][0] = fmaf(tv.x, wv.y, acc[1][0]); acc[1][1] = fmaf(tv.y, wv.y, acc[1][1]);
    acc[1][2] = fmaf(tv.z, wv.y, acc[1][2]); acc[1][3] = fmaf(tv.w, wv.y, acc[1][3]);
    acc[2][0] = fmaf(tv.x, wv.z, acc[2][0]); acc[2][1] = fmaf(tv.y, wv.z, acc[2][1]);
    acc[2][2] = fmaf(tv.z, wv.z, acc[2][2]); acc[2][3] = fmaf(tv.w, wv.z, acc[2][3]);
    acc[3][0] = fmaf(tv.x, wv.w, acc[3][0]); acc[3][1] = fmaf(tv.y, wv.w, acc[3][1]);
    acc[3][2] = fmaf(tv.z, wv.w, acc[3][2]); acc[3][3] = fmaf(tv.w, wv.w, acc[3][3]);
  }
#pragma unroll
  for (int a = 0; a < 4; ++a) {
    int co = co0 + a;
    float s = g[co] * rsqrtf(vv[co] + 1e-5f);
    float bias = bb[co] - mm[co] * s;
    float4 o4;
    o4.x = fminf(fmaxf(acc[a][0] * s + bias, 0.f), 6.f);
    o4.y = fminf(fmaxf(acc[a][1] * s + bias, 0.f), 6.f);
    o4.z = fminf(fmaxf(acc[a][2] * s + bias, 0.f), 6.f);
    o4.w = fminf(fmaxf(acc[a][3] * s + bias, 0.f), 6.f);
    *(float4*)(out + ((size_t)(b * 256 + co)) * 4096 + px0) = o4;
  }
}

// ---------------- launcher ----------------
extern "C" void kernel_launch(void* const* d_in, const int* in_sizes, int n_in,
                              void* d_out, int out_size, void* d_ws, size_t ws_size,
                              hipStream_t stream) {
  if (ws_size < WS_FLOATS * sizeof(float)) return;

  const float* x      = (const float*)d_in[0];
  const float* down_w = (const float*)d_in[1];
  const float* down_b = (const float*)d_in[2];
  const float* up_w   = (const float*)d_in[3];
  const float* up_b   = (const float*)d_in[4];
  const float* cqkv_w = (const float*)d_in[5];
  const float* cqkv_b = (const float*)d_in[6];
  const float* tqkv_w = (const float*)d_in[7];
  const float* tqkv_b = (const float*)d_in[8];
  const float* dww    = (const float*)d_in[9];
  const float* bn1g   = (const float*)d_in[10];
  const float* bn1b   = (const float*)d_in[11];
  const float* bn1m   = (const float*)d_in[12];
  const float* bn1v   = (const float*)d_in[13];
  const float* pww    = (const float*)d_in[14];
  const float* bn2g   = (const float*)d_in[15];
  const float* bn2b   = (const float*)d_in[16];
  const float* bn2m   = (const float*)d_in[17];
  const float* bn2v   = (const float*)d_in[18];

  float* ws    = (float*)d_ws;
  float* xdT   = ws + OFF_XD;
  float* q     = ws + OFF_Q;
  float* k     = ws + OFF_K;
  float* v     = ws + OFF_V;
  float* att   = ws + OFF_ATT;
  float* spart = ws + OFF_SPART;
  float* score = ws + OFF_SCORE;
  int*   idx   = (int*)(ws + OFF_IDX);
  float* cout  = ws + OFF_COUT;
  float* y     = ws + OFF_Y;
  float* t1    = ws + OFF_T1;
  float* dwt   = ws + OFF_SPART;             // dead after k_conv_down3
  float* attT  = ws + OFF_SPART + 2097152;   // upper half of spart region
  float* wt    = ws + OFF_XD;                // xdT dead after k_qkv_coarse
  float* coutT = ws + OFF_T1;                // t1 region dead until k_dw

  k_wt_dn<<<4096, 256, 0, stream>>>(down_w, dwt);
  k_conv_down3<<<512, 256, 0, stream>>>(x, dwt, down_b, xdT);
  k_qkv_coarse<<<32768, 192, 0, stream>>>(xdT, cqkv_w, cqkv_b, q, k, v);
  k_wt_up<<<4096, 256, 0, stream>>>(up_w, wt);          // overwrites xdT region
  k_attn3<true><<<512, 256, 0, stream>>>(q, k, v, att, spart, attT);
  k_score_reduce<<<128, 256, 0, stream>>>(spart, score);
  k_idx_init<<<32, 256, 0, stream>>>(idx);
  k_topk<<<32, 1024, 0, stream>>>(score, idx);
  k_conv_up3<<<2048, 256, 0, stream>>>(attT, wt, up_b, cout, coutT);
  k_qkv_topk<<<32768, 192, 0, stream>>>(coutT, idx, tqkv_w, tqkv_b, q, k, v);
  k_attn3<false><<<512, 256, 0, stream>>>(q, k, v, att, spart, attT);
  k_ybuild<<<32768, 256, 0, stream>>>(cout, y);
  k_scatter<<<8192, 256, 0, stream>>>(att, idx, y);
  k_dw<<<32768, 256, 0, stream>>>(y, dww, bn1g, bn1b, bn1m, bn1v, t1);
  k_pw2<<<2048, 256, 0, stream>>>(t1, pww, bn2g, bn2b, bn2m, bn2v, (float*)d_out);
}